// Round 12
// baseline (358.437 us; speedup 1.0000x reference)
//
#include <hip/hip_runtime.h>
#include <hip/hip_bf16.h>

typedef __bf16 bf16_t;
typedef __attribute__((ext_vector_type(8))) __bf16 bf16x8;
typedef __attribute__((ext_vector_type(4))) __bf16 bf16x4;
typedef __attribute__((ext_vector_type(4))) float floatx4;

// B=8, N=4096, D=CV=128. fp32 in/out; bf16 MFMA compute, fp32 accumulate.
static constexpr int NSEQ = 4096;
static constexpr int DIM  = 128;
static constexpr int BATCH = 8;
static constexpr size_t NELEM = (size_t)BATCH * NSEQ * DIM;
static constexpr size_t WS_NEED = 2 * NELEM * sizeof(bf16_t);   // Kb + Vt = 16 MiB

// ---- split-K over 64-row q-tiles (64 per batch), 64-key tiles, band 16 ----
// nch = qt/16 + 1 (1..4); NSLOT = sum = 160/batch; grid 1280.
static constexpr int NSLOT = 160;
static constexpr size_t WS_SPLITK =
    WS_NEED + (size_t)BATCH * NSLOT * (8192 + 64) * sizeof(float);   // ~59.0 MB (proven)

// 1/sqrt(128) * log2(e); folded into Q so the inner loop is bare exp2.
static constexpr float SCALE_LOG2E = 0.08838834764831845f * 1.4426950408889634f;

// S(qt) = slots before q-tile qt; g=qt/16, r=qt%16  (round-0 closed form, verified)
__device__ __forceinline__ int slot_base(int qt) {
  int g = qt >> 4, r = qt & 15;
  return qt + 8 * g * (g - 1) + r * g;
}

// async global->LDS, 16B per lane; LDS dest = wave-uniform base + lane*16
__device__ __forceinline__ void gld16(bf16_t* l, const bf16_t* g) {
  __builtin_amdgcn_global_load_lds(
      (const __attribute__((address_space(1))) unsigned int*)g,
      (__attribute__((address_space(3))) unsigned int*)l, 16, 0, 0);
}

__device__ __forceinline__ bf16x8 ld8_f32s(const float* p, float s) {
  float4 a = *(const float4*)p;
  float4 b = *(const float4*)(p + 4);
  bf16x8 r = {(__bf16)(a.x * s), (__bf16)(a.y * s), (__bf16)(a.z * s), (__bf16)(a.w * s),
              (__bf16)(b.x * s), (__bf16)(b.y * s), (__bf16)(b.z * s), (__bf16)(b.w * s)};
  return r;
}

// ---------------- prep: K fp32->bf16, V fp32 -> Vt bf16 [B][dim][key] ----------------
// Also zeroes the 512 fused-combine counters (carved from the never-written
// qt<16 slot-0 region of Pp); prep precedes attn on the stream -> ordering safe.
// NOTE: block is 256 threads -> each thread zeroes TWO counters (r11 bug fix).

__global__ __launch_bounds__(256)
void prep_kernel(const float* __restrict__ K, const float* __restrict__ V,
                 bf16_t* __restrict__ Kb, bf16_t* __restrict__ Vt,
                 float* __restrict__ Pp) {
  __shared__ bf16_t ldsT[128 * 66];       // [dim][key], stride 66 to spread banks
  const int bid = blockIdx.x;
  if (Pp != nullptr && bid == 0) {        // per-(b,qt) finisher counters: 512 ints
    ((int*)Pp)[threadIdx.x] = 0;
    ((int*)Pp)[256 + threadIdx.x] = 0;
  }
  if (bid < 1536) {                       // K convert, grid-stride, 16B stores
    const size_t n8 = NELEM / 8;
    for (size_t i = (size_t)bid * 256 + threadIdx.x; i < n8; i += (size_t)1536 * 256) {
      float4 a = ((const float4*)K)[2 * i];
      float4 c = ((const float4*)K)[2 * i + 1];
      bf16x8 kv = {(__bf16)a.x, (__bf16)a.y, (__bf16)a.z, (__bf16)a.w,
                   (__bf16)c.x, (__bf16)c.y, (__bf16)c.z, (__bf16)c.w};
      ((bf16x8*)Kb)[i] = kv;
    }
  } else {                                // V transpose+convert, one 64-key tile/block
    const int id = bid - 1536;            // 0..511
    const int b  = id & 7;
    const int kt = id >> 3;               // 0..63
    const float* src = V + ((size_t)(b * NSEQ + kt * 64)) * DIM;
    #pragma unroll
    for (int it = 0; it < 8; ++it) {
      const int idx = it * 256 + (int)threadIdx.x;   // 0..2047 float4
      const int k = idx >> 5, c4 = idx & 31;
      float4 v = ((const float4*)src)[idx];
      ldsT[(c4 * 4 + 0) * 66 + k] = (__bf16)v.x;
      ldsT[(c4 * 4 + 1) * 66 + k] = (__bf16)v.y;
      ldsT[(c4 * 4 + 2) * 66 + k] = (__bf16)v.z;
      ldsT[(c4 * 4 + 3) * 66 + k] = (__bf16)v.w;
    }
    __syncthreads();
    #pragma unroll
    for (int it = 0; it < 4; ++it) {
      const int task = it * 256 + (int)threadIdx.x;  // 0..1023
      const int d = task >> 3, kg = task & 7;
      bf16x8 o;
      #pragma unroll
      for (int j = 0; j < 8; ++j) o[j] = ldsT[d * 66 + kg * 8 + j];
      *(bf16x8*)(Vt + ((size_t)b * DIM + d) * NSEQ + kt * 64 + kg * 8) = o;
    }
  }
}

// ---------------- per-tile compute: 16q x 64k per wave, swapped QK^T, in-reg P ----------------
// K staged with row permutation pi so each lane's QK^T outputs ARE its PV A-fragment
// (keys 32h+8quad+4cc+r, lane-local); lane's q-column is l16. Verbatim best (r8).

template <bool MASK>
__device__ __forceinline__ void tile16(
    const bf16_t* __restrict__ kbuf, const bf16_t* __restrict__ vbuf,
    const bf16x8 (&qf)[4], int l16, int quad, int wq16,
    floatx4 (&acc)[8], float& lsum) {
  #pragma unroll
  for (int h = 0; h < 2; ++h) {           // key half: 32h .. 32h+31
    float pr[8];                          // lane-local P values, keys 32h+8quad+{0..7}
    #pragma unroll
    for (int cc = 0; cc < 2; ++cc) {
      const int c4 = 2 * h + cc;
      floatx4 sv = {0.f, 0.f, 0.f, 0.f};
      const bf16_t* krow = kbuf + (c4 * 16 + l16) * DIM;
      #pragma unroll
      for (int d = 0; d < 4; ++d) {
        bf16x8 kf = *(const bf16x8*)(krow + (((4 * d + quad) ^ l16) * 8));
        sv = __builtin_amdgcn_mfma_f32_16x16x32_bf16(kf, qf[d], sv, 0, 0, 0);
      }
      #pragma unroll
      for (int r = 0; r < 4; ++r) {
        float v = sv[r];
        if constexpr (MASK) {
          const int key = 32 * h + 8 * quad + 4 * cc + r;        // pi-mapped key
          v = (key <= wq16 + l16) ? v : -3.0e38f;                // exp2 -> 0
        }
        float p = __builtin_amdgcn_exp2f(v);
        lsum += p;
        pr[4 * cc + r] = p;
      }
    }
    bf16x8 pf;
    #pragma unroll
    for (int j = 0; j < 8; ++j) pf[j] = (__bf16)pr[j];
    // ---- O += P(:,32h..32h+31) * V(32h..32h+31,:) ----
    __builtin_amdgcn_s_setprio(1);
    #pragma unroll
    for (int c = 0; c < 8; ++c) {
      const bf16_t* vrow = vbuf + (c * 16 + l16) * 64;
      bf16x8 vf = *(const bf16x8*)(vrow + (((quad + 4 * h) ^ (l16 & 7)) * 8));
      acc[c] = __builtin_amdgcn_mfma_f32_16x16x32_bf16(pf, vf, acc[c], 0, 0, 0);
    }
    __builtin_amdgcn_s_setprio(0);
  }
}

// ---------------- split-K attention: K-dbuf LDS + V reg-staged (48 KB), FUSED combine ----------------
// Inner loop verbatim from the best-measured kernel (153.9 us total). Epilogue:
// multi-chunk tiles write partials, fence, bump a device-scope counter; the last
// finisher per (b,qt) reduces all chunks and writes the output tile inline.

__global__ __launch_bounds__(256, 3)
void causal_attn_splitk(const float* __restrict__ Qf, const bf16_t* __restrict__ Kb,
                        const bf16_t* __restrict__ Vt, float* __restrict__ Out,
                        float* __restrict__ Pp, float* __restrict__ Ls) {
  __shared__ __align__(16) bf16_t Kds[2][64 * DIM];   // 2 x 16 KB
  __shared__ __align__(16) bf16_t Vds[DIM * 64];      // 16 KB -> 48 KB total
  __shared__ int is_last;

  const int b = (int)blockIdx.x & 7;                  // batch -> XCD (L2 affinity)
  const int s = (NSLOT - 1) - ((int)blockIdx.x >> 3); // longest chunks first
  int qt = 63, cch = 0;
  {
    int acc0 = 0;                                     // decode s -> (qt, chunk)
    #pragma unroll
    for (int g = 0; g < 4; ++g) {
      const int bandw = 16 * (g + 1);
      if (s < acc0 + bandw) {
        const int u = s - acc0;
        qt = g * 16 + u / (g + 1);
        cch = u % (g + 1);
        break;
      }
      acc0 += bandw;
    }
  }
  const int ntot = qt + 1;                            // 64-key tiles for this q-tile
  const int nch  = (qt >> 4) + 1;
  const int nt_c = (ntot - 1 - cch) / nch + 1;        // tiles in this (strided) chunk
  const int nmask = (cch + (nt_c - 1) * nch == qt) ? 1 : 0;
  const int nfull = nt_c - nmask;

  const int tid  = (int)threadIdx.x;
  const int wave = tid >> 6;
  const int lane = tid & 63;
  const int l16  = lane & 15;
  const int quad = lane >> 4;
  const int wq16 = wave * 16;                         // wave's 16 q-rows within tile

  // Q fragments (B-operand): lane(l16,quad) = Q[q=wq16+l16][dims 32d+8quad..+8]
  bf16x8 qf[4];
  {
    const float* qrow =
        Qf + ((size_t)b * NSEQ + qt * 64 + wq16 + l16) * DIM + quad * 8;
    #pragma unroll
    for (int d = 0; d < 4; ++d) qf[d] = ld8_f32s(qrow + 32 * d, SCALE_LOG2E);
  }

  // staging: K rows permuted by pi, dim chunks XOR'd on SOURCE (gld16, linear dest).
  // V: prologue via gld16 (source-XOR); steady-state via regs: LINEAR global source,
  // XOR applied on the ds_write DEST. Readers unchanged.
  const bf16_t* kg = Kb + (size_t)b * NSEQ * DIM;
  const bf16_t* vg = Vt + ((size_t)b * DIM + 32 * wave) * NSEQ;
  int koff[4], voff[4], vsrc[4], vdst[4];
  #pragma unroll
  for (int i = 0; i < 4; ++i) {
    const int p    = 16 * wave + 4 * i + quad;
    const int srow = 32 * (wave >> 1) + 8 * i + 4 * (wave & 1) + quad;  // pi(p)
    koff[i] = srow * DIM + ((l16 ^ (p & 15)) * 8);
    const int vrow = 8 * i + (lane >> 3);              // 0..31
    voff[i] = vrow * NSEQ + (((lane & 7) ^ (vrow & 7)) * 8);            // gld16 source
    vsrc[i] = vrow * NSEQ + (lane & 7) * 8;                             // reg source
    vdst[i] = (32 * wave + vrow) * 64 + (((lane & 7) ^ (vrow & 7)) * 8);// ds_write dest
  }

  floatx4 acc[8];
  #pragma unroll
  for (int c = 0; c < 8; ++c) acc[c] = (floatx4){0.f, 0.f, 0.f, 0.f};
  float lsum = 0.f;

  // prologue: stage tile cch (K -> buf 0, V -> single buffer), both via gld16
  {
    const size_t kb0 = (size_t)cch * 64;
    bf16_t* kl = &Kds[0][wave * 2048];
    bf16_t* vl = &Vds[wave * 2048];
    #pragma unroll
    for (int i = 0; i < 4; ++i) {
      gld16(kl + i * 512, kg + kb0 * DIM + koff[i]);
      gld16(vl + i * 512, vg + kb0 + voff[i]);
    }
  }
  __syncthreads();                        // drains vmcnt -> tile 0 ready

  bf16x8 vreg[4];
  int t = cch;
  for (int it = 0; it < nt_c; ++it, t += nch) {
    const int cur = it & 1;
    const bool more = (it + 1 < nt_c);    // block-uniform
    const size_t kbn = (size_t)(t + nch) * 64;
    if (more) {                           // K prefetch (LDS-direct) + V load-to-reg,
      bf16_t* kl = &Kds[cur ^ 1][wave * 2048];       // both hidden under compute
      #pragma unroll
      for (int i = 0; i < 4; ++i) gld16(kl + i * 512, kg + kbn * DIM + koff[i]);
      #pragma unroll
      for (int i = 0; i < 4; ++i) vreg[i] = *(const bf16x8*)(vg + kbn + vsrc[i]);
    }
    __builtin_amdgcn_sched_barrier(0);    // loads issue before compute
    if (it < nfull)
      tile16<false>(Kds[cur], Vds, qf, l16, quad, wq16, acc, lsum);
    else
      tile16<true>(Kds[cur], Vds, qf, l16, quad, wq16, acc, lsum);
    __builtin_amdgcn_sched_barrier(0);
    __builtin_amdgcn_s_barrier();         // all waves done reading Vds / Kds[cur]
    if (more) {
      // ds_write forces vmcnt wait on V regs (youngest) -> older K gld16 also retired
      #pragma unroll
      for (int i = 0; i < 4; ++i) *(bf16x8*)(&Vds[vdst[i]]) = vreg[i];
      asm volatile("s_waitcnt lgkmcnt(0)" ::: "memory");  // writes visible pre-barrier
      __builtin_amdgcn_sched_barrier(0);
      __builtin_amdgcn_s_barrier();       // staged tile visible to all waves
    }
  }

  // ---- l-reduction across quads (q = l16 per wave) ----
  float lred = lsum;
  lred += __shfl_xor(lred, 16, 64);
  lred += __shfl_xor(lred, 32, 64);

  if (nch == 1) {                                     // single chunk: direct output
    float invl[4];
    #pragma unroll
    for (int r = 0; r < 4; ++r)
      invl[r] = 1.0f / __shfl(lred, quad * 4 + r, 64);
    float* orow =
        Out + ((size_t)b * NSEQ + qt * 64 + wq16 + quad * 4) * DIM + l16;
    #pragma unroll
    for (int c = 0; c < 8; ++c)
      #pragma unroll
      for (int r = 0; r < 4; ++r)
        orow[(size_t)r * DIM + c * 16] = acc[c][r] * invl[r];
  } else {                                            // partials + fused combine
    const int s0   = b * NSLOT + slot_base(qt);
    const int slot = s0 + cch;
    float* pb = Pp + (size_t)slot * 8192 +
                ((size_t)(wq16 + quad * 4)) * 128 + l16;
    #pragma unroll
    for (int c = 0; c < 8; ++c)
      #pragma unroll
      for (int r = 0; r < 4; ++r)
        pb[(size_t)r * 128 + c * 16] = acc[c][r];
    if (quad == 0)
      Ls[(size_t)slot * 64 + wq16 + l16] = lred;

    // signal chunk completion (device-scope); counters live in Pp slot-0 region
    __threadfence();                      // release: partials visible device-wide
    __syncthreads();                      // all waves' stores fenced
    if (tid == 0)
      is_last = (atomicAdd(&((int*)Pp)[b * 64 + qt], 1) == nch - 1);
    __syncthreads();
    if (is_last) {                        // last finisher reduces the whole q-tile
      __threadfence();                    // acquire: other chunks' partials visible
      #pragma unroll
      for (int j = 0; j < 8; ++j) {
        const int idx = j * 256 + tid;    // 0..2047 float4 (64q x 32)
        const int q   = idx >> 5;
        const int d4  = idx & 31;
        float4 v = {0.f, 0.f, 0.f, 0.f};
        float  l = 0.f;
        for (int ch = 0; ch < nch; ++ch) {
          const float* pc = Pp + (size_t)(s0 + ch) * 8192 + (size_t)q * 128 + d4 * 4;
          float4 a = *(const float4*)pc;
          v.x += a.x; v.y += a.y; v.z += a.z; v.w += a.w;
          l += Ls[(size_t)(s0 + ch) * 64 + q];
        }
        const float inv = 1.0f / l;
        float4 r = {v.x * inv, v.y * inv, v.z * inv, v.w * inv};
        *(float4*)(Out + ((size_t)b * NSEQ + qt * 64 + q) * DIM + d4 * 4) = r;
      }
    }
  }
}

// ---------------- middle tier: round-1 64q-row kernel (16.8MB <= ws < 59MB) ----------------

template <bool MASK>
__device__ __forceinline__ void tile_compute(
    const bf16_t* __restrict__ kbuf, const bf16_t* __restrict__ vbuf,
    bf16_t* __restrict__ pl, const bf16x8 (&qf)[4],
    int l16, int quad, int wq, floatx4 (&acc)[8], float (&lsum)[4]) {
  floatx4 s[4];
  #pragma unroll
  for (int c4 = 0; c4 < 4; ++c4) s[c4] = (floatx4){0.f, 0.f, 0.f, 0.f};
  #pragma unroll
  for (int c4 = 0; c4 < 4; ++c4) {
    const bf16_t* krow = kbuf + (c4 * 16 + l16) * DIM;
    #pragma unroll
    for (int d = 0; d < 4; ++d) {
      bf16x8 kf = *(const bf16x8*)(krow + (((4 * d + quad) ^ l16) * 8));
      s[c4] = __builtin_amdgcn_mfma_f32_16x16x32_bf16(qf[d], kf, s[c4], 0, 0, 0);
    }
  }
  #pragma unroll
  for (int c4 = 0; c4 < 4; ++c4) {
    #pragma unroll
    for (int r = 0; r < 4; ++r) {
      float v = s[c4][r];
      if constexpr (MASK)
        v = (c4 * 16 + l16 <= wq + quad * 4 + r) ? v : -3.0e38f;
      float p = __builtin_amdgcn_exp2f(v);
      lsum[r] += p;
      pl[(quad * 4 + r) * 72 + c4 * 16 + l16] = (__bf16)p;
    }
  }
  asm volatile("s_waitcnt lgkmcnt(0)" ::: "memory");
  bf16x8 pfA = *(const bf16x8*)(pl + l16 * 72 + quad * 8);
  bf16x8 pfB = *(const bf16x8*)(pl + l16 * 72 + 32 + quad * 8);
  #pragma unroll
  for (int c = 0; c < 8; ++c) {
    const bf16_t* vrow = vbuf + (c * 16 + l16) * 64;
    bf16x8 vfA = *(const bf16x8*)(vrow + ((quad ^ (l16 & 7)) * 8));
    bf16x8 vfB = *(const bf16x8*)(vrow + (((quad + 4) ^ (l16 & 7)) * 8));
    acc[c] = __builtin_amdgcn_mfma_f32_16x16x32_bf16(pfA, vfA, acc[c], 0, 0, 0);
    acc[c] = __builtin_amdgcn_mfma_f32_16x16x32_bf16(pfB, vfB, acc[c], 0, 0, 0);
  }
}

__global__ __launch_bounds__(256)
void causal_attn_kernel(const float* __restrict__ Qf, const bf16_t* __restrict__ Kb,
                        const bf16_t* __restrict__ Vt, float* __restrict__ Out) {
  __shared__ __align__(16) bf16_t Kbuf[64 * DIM];
  __shared__ __align__(16) bf16_t Vbuf[DIM * 64];
  __shared__ __align__(16) bf16_t Pbuf[4][16 * 72];

  const int half = blockIdx.x >> 8;
  const int idx  = blockIdx.x & 255;
  const int b    = idx & 7;
  const int q32  = idx >> 3;
  const int qt64 = half ? q32 : 63 - q32;

  const int tid  = (int)threadIdx.x;
  const int wave = tid >> 6;
  const int lane = tid & 63;
  const int l16  = lane & 15;
  const int quad = lane >> 4;
  const int wq   = wave * 16;

  bf16x8 qf[4];
  {
    const float* qrow = Qf + ((size_t)b * NSEQ + qt64 * 64 + wq + l16) * DIM + quad * 8;
    #pragma unroll
    for (int d = 0; d < 4; ++d) qf[d] = ld8_f32s(qrow + 32 * d, SCALE_LOG2E);
  }

  const bf16_t* kg0 = Kb + ((size_t)b * NSEQ + 16 * wave) * DIM;
  const bf16_t* vg0 = Vt + ((size_t)b * DIM + 32 * wave) * NSEQ;
  int koff[4], voff[4];
  #pragma unroll
  for (int i = 0; i < 4; ++i) {
    const int krow = 4 * i + (lane >> 4);
    koff[i] = krow * DIM + (((lane & 15) ^ (krow & 15)) * 8);
    const int vrow = 8 * i + (lane >> 3);
    voff[i] = vrow * NSEQ + (((lane & 7) ^ ((lane >> 3) & 7)) * 8);
  }
  bf16_t* kl = Kbuf + 16 * wave * DIM;
  bf16_t* vl = Vbuf + 32 * wave * 64;
  bf16_t* pl = Pbuf[wave];

  floatx4 acc[8];
  #pragma unroll
  for (int c = 0; c < 8; ++c) acc[c] = (floatx4){0.f, 0.f, 0.f, 0.f};
  float lsum[4] = {0.f, 0.f, 0.f, 0.f};

  const int nk = qt64 + 1;
  for (int kt = 0; kt < nk - 1; ++kt) {
    const int kb = kt * 64;
    #pragma unroll
    for (int i = 0; i < 4; ++i) gld16(kl + i * 512, kg0 + (size_t)kb * DIM + koff[i]);
    #pragma unroll
    for (int i = 0; i < 4; ++i) gld16(vl + i * 512, vg0 + kb + voff[i]);
    __syncthreads();
    tile_compute<false>(Kbuf, Vbuf, pl, qf, l16, quad, wq, acc, lsum);
    __syncthreads();
  }
  {
    const int kb = (nk - 1) * 64;
    #pragma unroll
    for (int i = 0; i < 4; ++i) gld16(kl + i * 512, kg0 + (size_t)kb * DIM + koff[i]);
    #pragma unroll
    for (int i = 0; i < 4; ++i) gld16(vl + i * 512, vg0 + kb + voff[i]);
    __syncthreads();
    tile_compute<true>(Kbuf, Vbuf, pl, qf, l16, quad, wq, acc, lsum);
  }

  float inv_l[4];
  #pragma unroll
  for (int r = 0; r < 4; ++r) {
    float s = lsum[r];
    #pragma unroll
    for (int off = 1; off < 16; off <<= 1) s += __shfl_xor(s, off, 64);
    inv_l[r] = 1.0f / s;
  }
  float* orow = Out + ((size_t)b * NSEQ + qt64 * 64 + wq + quad * 4) * DIM + l16;
  #pragma unroll
  for (int c = 0; c < 8; ++c) {
    #pragma unroll
    for (int r = 0; r < 4; ++r)
      orow[(size_t)r * DIM + c * 16] = acc[c][r] * inv_l[r];
  }
}

// ---------------- fallback (no workspace): fp32 direct ----------------

__global__ __launch_bounds__(256)
void causal_attn_fb(const float* __restrict__ Qf, const float* __restrict__ Kf,
                    const float* __restrict__ Vf, float* __restrict__ Out) {
  __shared__ bf16_t p_lds[4][16 * 72];
  const int bid = blockIdx.x, t = bid >> 3, b = bid & 7;
  const int tid = (int)threadIdx.x, wave = tid >> 6, lane = tid & 63;
  const int l16 = lane & 15, quad = lane >> 4;
  const int qtile = (wave < 2) ? t : (127 - t);
  const int q_base = qtile * 32 + (wave & 1) * 16;

  bf16x8 qf[4];
  const float* qrow = Qf + ((size_t)b * NSEQ + q_base + l16) * DIM + quad * 8;
  #pragma unroll
  for (int d = 0; d < 4; ++d) qf[d] = ld8_f32s(qrow + 32 * d, SCALE_LOG2E);

  floatx4 acc[8];
  #pragma unroll
  for (int c = 0; c < 8; ++c) acc[c] = (floatx4){0.f, 0.f, 0.f, 0.f};
  float lsum[4] = {0.f, 0.f, 0.f, 0.f};
  bf16_t* pl = p_lds[wave];
  const int ntiles = (q_base + 16 + 63) >> 6;

  for (int kt = 0; kt < ntiles; ++kt) {
    const int kb = kt * 64;
    floatx4 s[4];
    #pragma unroll
    for (int c4 = 0; c4 < 4; ++c4) s[c4] = (floatx4){0.f, 0.f, 0.f, 0.f};
    const float* kbase = Kf + ((size_t)b * NSEQ + kb + l16) * DIM + quad * 8;
    #pragma unroll
    for (int c4 = 0; c4 < 4; ++c4) {
      #pragma unroll
      for (int d = 0; d < 4; ++d) {
        bf16x8 kf = ld8_f32s(kbase + (size_t)c4 * 16 * DIM + 32 * d, 1.0f);
        s[c4] = __builtin_amdgcn_mfma_f32_16x16x32_bf16(qf[d], kf, s[c4], 0, 0, 0);
      }
    }
    #pragma unroll
    for (int c4 = 0; c4 < 4; ++c4) {
      #pragma unroll
      for (int r = 0; r < 4; ++r) {
        float v = s[c4][r];
        const int qi = q_base + quad * 4 + r;
        v = (kb + c4 * 16 + l16 <= qi) ? v : -3.0e38f;
        float p = __builtin_amdgcn_exp2f(v);
        lsum[r] += p;
        pl[(quad * 4 + r) * 72 + c4 * 16 + l16] = (__bf16)p;
      }
    }
    asm volatile("s_waitcnt lgkmcnt(0)" ::: "memory");
    bf16x8 pfA = *(const bf16x8*)(pl + l16 * 72 + quad * 8);
    bf16x8 pfB = *(const bf16x8*)(pl + l16 * 72 + 32 + quad * 8);
    const float* vb = Vf + ((size_t)b * NSEQ + kb) * DIM;
    #pragma unroll
    for (int c = 0; c < 8; ++c) {
      bf16x8 vfA, vfB;
      #pragma unroll
      for (int j = 0; j < 8; ++j) {
        vfA[j] = (__bf16)vb[(size_t)(quad * 8 + j) * DIM + c * 16 + l16];
        vfB[j] = (__bf16)vb[(size_t)(32 + quad * 8 + j) * DIM + c * 16 + l16];
      }
      acc[c] = __builtin_amdgcn_mfma_f32_16x16x32_bf16(pfA, vfA, acc[c], 0, 0, 0);
      acc[c] = __builtin_amdgcn_mfma_f32_16x16x32_bf16(pfB, vfB, acc[c], 0, 0, 0);
    }
  }
  float inv_l[4];
  #pragma unroll
  for (int r = 0; r < 4; ++r) {
    float s = lsum[r];
    #pragma unroll
    for (int off = 1; off < 16; off <<= 1) s += __shfl_xor(s, off, 64);
    inv_l[r] = 1.0f / s;
  }
  float* orow = Out + ((size_t)b * NSEQ + q_base + quad * 4) * DIM + l16;
  #pragma unroll
  for (int c = 0; c < 8; ++c) {
    #pragma unroll
    for (int r = 0; r < 4; ++r)
      orow[(size_t)r * DIM + c * 16] = acc[c][r] * inv_l[r];
  }
}

extern "C" void kernel_launch(void* const* d_in, const int* in_sizes, int n_in,
                              void* d_out, int out_size, void* d_ws, size_t ws_size,
                              hipStream_t stream) {
  const float* Q = (const float*)d_in[0];
  const float* K = (const float*)d_in[1];
  const float* V = (const float*)d_in[2];
  float* Out = (float*)d_out;
  (void)in_sizes; (void)n_in; (void)out_size;

  dim3 block(256);
  if (ws_size >= WS_SPLITK) {
    bf16_t* Kb = (bf16_t*)d_ws;
    bf16_t* Vt = Kb + NELEM;
    float*  Pp = (float*)((char*)d_ws + WS_NEED);
    float*  Ls = Pp + (size_t)BATCH * NSLOT * 8192;
    prep_kernel<<<dim3(2048), block, 0, stream>>>(K, V, Kb, Vt, Pp);
    causal_attn_splitk<<<dim3(BATCH * NSLOT), block, 0, stream>>>(Q, Kb, Vt, Out, Pp, Ls);
  } else if (ws_size >= WS_NEED) {
    bf16_t* Kb = (bf16_t*)d_ws;
    bf16_t* Vt = Kb + NELEM;
    prep_kernel<<<dim3(2048), block, 0, stream>>>(K, V, Kb, Vt, nullptr);
    causal_attn_kernel<<<dim3(512), block, 0, stream>>>(Q, Kb, Vt, Out);
  } else {
    causal_attn_fb<<<dim3(512), block, 0, stream>>>(Q, K, V, Out);
  }
}

// Round 13
// 152.908 us; speedup vs baseline: 2.3441x; 2.3441x over previous
//
#include <hip/hip_runtime.h>
#include <hip/hip_bf16.h>

typedef __bf16 bf16_t;
typedef __attribute__((ext_vector_type(8))) __bf16 bf16x8;
typedef __attribute__((ext_vector_type(4))) __bf16 bf16x4;
typedef __attribute__((ext_vector_type(4))) float floatx4;

// B=8, N=4096, D=CV=128. fp32 in/out; bf16 MFMA compute, fp32 accumulate.
static constexpr int NSEQ = 4096;
static constexpr int DIM  = 128;
static constexpr int BATCH = 8;
static constexpr size_t NELEM = (size_t)BATCH * NSEQ * DIM;
static constexpr size_t WS_NEED = 2 * NELEM * sizeof(bf16_t);   // Kb + Vt = 16 MiB

// ---- split-K over 64-row q-tiles (64 per batch), 64-key tiles, band 16 ----
// nch = qt/16 + 1 (1..4); NSLOT = sum = 160/batch; grid 1280.
static constexpr int NSLOT = 160;
static constexpr size_t WS_SPLITK =
    WS_NEED + (size_t)BATCH * NSLOT * (8192 + 64) * sizeof(float);   // ~59.0 MB (proven)

// 1/sqrt(128) * log2(e); folded into Q so the inner loop is bare exp2.
static constexpr float SCALE_LOG2E = 0.08838834764831845f * 1.4426950408889634f;

// S(qt) = slots before q-tile qt; g=qt/16, r=qt%16  (round-0 closed form, verified)
__device__ __forceinline__ int slot_base(int qt) {
  int g = qt >> 4, r = qt & 15;
  return qt + 8 * g * (g - 1) + r * g;
}

// async global->LDS, 16B per lane; LDS dest = wave-uniform base + lane*16
__device__ __forceinline__ void gld16(bf16_t* l, const bf16_t* g) {
  __builtin_amdgcn_global_load_lds(
      (const __attribute__((address_space(1))) unsigned int*)g,
      (__attribute__((address_space(3))) unsigned int*)l, 16, 0, 0);
}

__device__ __forceinline__ bf16x8 ld8_f32s(const float* p, float s) {
  float4 a = *(const float4*)p;
  float4 b = *(const float4*)(p + 4);
  bf16x8 r = {(__bf16)(a.x * s), (__bf16)(a.y * s), (__bf16)(a.z * s), (__bf16)(a.w * s),
              (__bf16)(b.x * s), (__bf16)(b.y * s), (__bf16)(b.z * s), (__bf16)(b.w * s)};
  return r;
}

// ---------------- prep: K fp32->bf16 (16B stores), V fp32 -> Vt bf16 [B][dim][key] ----------------

__global__ __launch_bounds__(256)
void prep_kernel(const float* __restrict__ K, const float* __restrict__ V,
                 bf16_t* __restrict__ Kb, bf16_t* __restrict__ Vt) {
  __shared__ bf16_t ldsT[128 * 66];       // [dim][key], stride 66 to spread banks
  const int bid = blockIdx.x;
  if (bid < 1536) {                       // K convert, grid-stride, 16B stores
    const size_t n8 = NELEM / 8;
    for (size_t i = (size_t)bid * 256 + threadIdx.x; i < n8; i += (size_t)1536 * 256) {
      float4 a = ((const float4*)K)[2 * i];
      float4 c = ((const float4*)K)[2 * i + 1];
      bf16x8 kv = {(__bf16)a.x, (__bf16)a.y, (__bf16)a.z, (__bf16)a.w,
                   (__bf16)c.x, (__bf16)c.y, (__bf16)c.z, (__bf16)c.w};
      ((bf16x8*)Kb)[i] = kv;
    }
  } else {                                // V transpose+convert, one 64-key tile/block
    const int id = bid - 1536;            // 0..511
    const int b  = id & 7;
    const int kt = id >> 3;               // 0..63
    const float* src = V + ((size_t)(b * NSEQ + kt * 64)) * DIM;
    #pragma unroll
    for (int it = 0; it < 8; ++it) {
      const int idx = it * 256 + (int)threadIdx.x;   // 0..2047 float4
      const int k = idx >> 5, c4 = idx & 31;
      float4 v = ((const float4*)src)[idx];
      ldsT[(c4 * 4 + 0) * 66 + k] = (__bf16)v.x;
      ldsT[(c4 * 4 + 1) * 66 + k] = (__bf16)v.y;
      ldsT[(c4 * 4 + 2) * 66 + k] = (__bf16)v.z;
      ldsT[(c4 * 4 + 3) * 66 + k] = (__bf16)v.w;
    }
    __syncthreads();
    #pragma unroll
    for (int it = 0; it < 4; ++it) {
      const int task = it * 256 + (int)threadIdx.x;  // 0..1023
      const int d = task >> 3, kg = task & 7;
      bf16x8 o;
      #pragma unroll
      for (int j = 0; j < 8; ++j) o[j] = ldsT[d * 66 + kg * 8 + j];
      *(bf16x8*)(Vt + ((size_t)b * DIM + d) * NSEQ + kt * 64 + kg * 8) = o;
    }
  }
}

// ---------------- per-tile compute: 16q x 64k per wave, swapped QK^T, in-reg P ----------------
// K staged with row permutation pi so each lane's QK^T outputs ARE its PV A-fragment
// (keys 32h+8quad+4cc+r, lane-local); lane's q-column is l16. Verbatim best (r8).

template <bool MASK>
__device__ __forceinline__ void tile16(
    const bf16_t* __restrict__ kbuf, const bf16_t* __restrict__ vbuf,
    const bf16x8 (&qf)[4], int l16, int quad, int wq16,
    floatx4 (&acc)[8], float& lsum) {
  #pragma unroll
  for (int h = 0; h < 2; ++h) {           // key half: 32h .. 32h+31
    float pr[8];                          // lane-local P values, keys 32h+8quad+{0..7}
    #pragma unroll
    for (int cc = 0; cc < 2; ++cc) {
      const int c4 = 2 * h + cc;
      floatx4 sv = {0.f, 0.f, 0.f, 0.f};
      const bf16_t* krow = kbuf + (c4 * 16 + l16) * DIM;
      #pragma unroll
      for (int d = 0; d < 4; ++d) {
        bf16x8 kf = *(const bf16x8*)(krow + (((4 * d + quad) ^ l16) * 8));
        sv = __builtin_amdgcn_mfma_f32_16x16x32_bf16(kf, qf[d], sv, 0, 0, 0);
      }
      #pragma unroll
      for (int r = 0; r < 4; ++r) {
        float v = sv[r];
        if constexpr (MASK) {
          const int key = 32 * h + 8 * quad + 4 * cc + r;        // pi-mapped key
          v = (key <= wq16 + l16) ? v : -3.0e38f;                // exp2 -> 0
        }
        float p = __builtin_amdgcn_exp2f(v);
        lsum += p;
        pr[4 * cc + r] = p;
      }
    }
    bf16x8 pf;
    #pragma unroll
    for (int j = 0; j < 8; ++j) pf[j] = (__bf16)pr[j];
    // ---- O += P(:,32h..32h+31) * V(32h..32h+31,:) ----
    __builtin_amdgcn_s_setprio(1);
    #pragma unroll
    for (int c = 0; c < 8; ++c) {
      const bf16_t* vrow = vbuf + (c * 16 + l16) * 64;
      bf16x8 vf = *(const bf16x8*)(vrow + (((quad + 4 * h) ^ (l16 & 7)) * 8));
      acc[c] = __builtin_amdgcn_mfma_f32_16x16x32_bf16(pf, vf, acc[c], 0, 0, 0);
    }
    __builtin_amdgcn_s_setprio(0);
  }
}

// ---------------- split-K attention: K-dbuf LDS + V reg-staged (48 KB), 3 blk/CU ----------------
// T14: V(next) loaded to registers at step top (issue-early), ds_written after the
// post-compute barrier (write-late). Verbatim round-8 (best measured: 153.9 us total).

__global__ __launch_bounds__(256, 3)
void causal_attn_splitk(const float* __restrict__ Qf, const bf16_t* __restrict__ Kb,
                        const bf16_t* __restrict__ Vt, float* __restrict__ Out,
                        float* __restrict__ Pp, float* __restrict__ Ls) {
  __shared__ __align__(16) bf16_t Kds[2][64 * DIM];   // 2 x 16 KB
  __shared__ __align__(16) bf16_t Vds[DIM * 64];      // 16 KB -> 48 KB total

  const int b = (int)blockIdx.x & 7;                  // batch -> XCD (L2 affinity)
  const int s = (NSLOT - 1) - ((int)blockIdx.x >> 3); // longest chunks first
  int qt = 63, cch = 0;
  {
    int acc0 = 0;                                     // decode s -> (qt, chunk)
    #pragma unroll
    for (int g = 0; g < 4; ++g) {
      const int bandw = 16 * (g + 1);
      if (s < acc0 + bandw) {
        const int u = s - acc0;
        qt = g * 16 + u / (g + 1);
        cch = u % (g + 1);
        break;
      }
      acc0 += bandw;
    }
  }
  const int ntot = qt + 1;                            // 64-key tiles for this q-tile
  const int nch  = (qt >> 4) + 1;
  const int nt_c = (ntot - 1 - cch) / nch + 1;        // tiles in this (strided) chunk
  const int nmask = (cch + (nt_c - 1) * nch == qt) ? 1 : 0;
  const int nfull = nt_c - nmask;

  const int tid  = (int)threadIdx.x;
  const int wave = tid >> 6;
  const int lane = tid & 63;
  const int l16  = lane & 15;
  const int quad = lane >> 4;
  const int wq16 = wave * 16;                         // wave's 16 q-rows within tile

  // Q fragments (B-operand): lane(l16,quad) = Q[q=wq16+l16][dims 32d+8quad..+8]
  bf16x8 qf[4];
  {
    const float* qrow =
        Qf + ((size_t)b * NSEQ + qt * 64 + wq16 + l16) * DIM + quad * 8;
    #pragma unroll
    for (int d = 0; d < 4; ++d) qf[d] = ld8_f32s(qrow + 32 * d, SCALE_LOG2E);
  }

  // staging: K rows permuted by pi, dim chunks XOR'd on SOURCE (gld16, linear dest).
  // V: prologue via gld16 (source-XOR); steady-state via regs: LINEAR global source,
  // XOR applied on the ds_write DEST. Readers unchanged.
  const bf16_t* kg = Kb + (size_t)b * NSEQ * DIM;
  const bf16_t* vg = Vt + ((size_t)b * DIM + 32 * wave) * NSEQ;
  int koff[4], voff[4], vsrc[4], vdst[4];
  #pragma unroll
  for (int i = 0; i < 4; ++i) {
    const int p    = 16 * wave + 4 * i + quad;
    const int srow = 32 * (wave >> 1) + 8 * i + 4 * (wave & 1) + quad;  // pi(p)
    koff[i] = srow * DIM + ((l16 ^ (p & 15)) * 8);
    const int vrow = 8 * i + (lane >> 3);              // 0..31
    voff[i] = vrow * NSEQ + (((lane & 7) ^ (vrow & 7)) * 8);            // gld16 source
    vsrc[i] = vrow * NSEQ + (lane & 7) * 8;                             // reg source
    vdst[i] = (32 * wave + vrow) * 64 + (((lane & 7) ^ (vrow & 7)) * 8);// ds_write dest
  }

  floatx4 acc[8];
  #pragma unroll
  for (int c = 0; c < 8; ++c) acc[c] = (floatx4){0.f, 0.f, 0.f, 0.f};
  float lsum = 0.f;

  // prologue: stage tile cch (K -> buf 0, V -> single buffer), both via gld16
  {
    const size_t kb0 = (size_t)cch * 64;
    bf16_t* kl = &Kds[0][wave * 2048];
    bf16_t* vl = &Vds[wave * 2048];
    #pragma unroll
    for (int i = 0; i < 4; ++i) {
      gld16(kl + i * 512, kg + kb0 * DIM + koff[i]);
      gld16(vl + i * 512, vg + kb0 + voff[i]);
    }
  }
  __syncthreads();                        // drains vmcnt -> tile 0 ready

  bf16x8 vreg[4];
  int t = cch;
  for (int it = 0; it < nt_c; ++it, t += nch) {
    const int cur = it & 1;
    const bool more = (it + 1 < nt_c);    // block-uniform
    const size_t kbn = (size_t)(t + nch) * 64;
    if (more) {                           // K prefetch (LDS-direct) + V load-to-reg,
      bf16_t* kl = &Kds[cur ^ 1][wave * 2048];       // both hidden under compute
      #pragma unroll
      for (int i = 0; i < 4; ++i) gld16(kl + i * 512, kg + kbn * DIM + koff[i]);
      #pragma unroll
      for (int i = 0; i < 4; ++i) vreg[i] = *(const bf16x8*)(vg + kbn + vsrc[i]);
    }
    __builtin_amdgcn_sched_barrier(0);    // loads issue before compute
    if (it < nfull)
      tile16<false>(Kds[cur], Vds, qf, l16, quad, wq16, acc, lsum);
    else
      tile16<true>(Kds[cur], Vds, qf, l16, quad, wq16, acc, lsum);
    __builtin_amdgcn_sched_barrier(0);
    __builtin_amdgcn_s_barrier();         // all waves done reading Vds / Kds[cur]
    if (more) {
      // ds_write forces vmcnt wait on V regs (youngest) -> older K gld16 also retired
      #pragma unroll
      for (int i = 0; i < 4; ++i) *(bf16x8*)(&Vds[vdst[i]]) = vreg[i];
      asm volatile("s_waitcnt lgkmcnt(0)" ::: "memory");  // writes visible pre-barrier
      __builtin_amdgcn_sched_barrier(0);
      __builtin_amdgcn_s_barrier();       // staged tile visible to all waves
    }
  }

  // ---- l-reduction across quads (q = l16 per wave) ----
  float lred = lsum;
  lred += __shfl_xor(lred, 16, 64);
  lred += __shfl_xor(lred, 32, 64);

  if (nch == 1) {                                     // single chunk: direct output
    float invl[4];
    #pragma unroll
    for (int r = 0; r < 4; ++r)
      invl[r] = 1.0f / __shfl(lred, quad * 4 + r, 64);
    float* orow =
        Out + ((size_t)b * NSEQ + qt * 64 + wq16 + quad * 4) * DIM + l16;
    #pragma unroll
    for (int c = 0; c < 8; ++c)
      #pragma unroll
      for (int r = 0; r < 4; ++r)
        orow[(size_t)r * DIM + c * 16] = acc[c][r] * invl[r];
  } else {                                            // unnormalized partials
    const int slot = b * NSLOT + slot_base(qt) + cch;
    float* pb = Pp + (size_t)slot * 8192 +
                ((size_t)(wq16 + quad * 4)) * 128 + l16;
    #pragma unroll
    for (int c = 0; c < 8; ++c)
      #pragma unroll
      for (int r = 0; r < 4; ++r)
        pb[(size_t)r * 128 + c * 16] = acc[c][r];
    if (quad == 0)
      Ls[(size_t)slot * 64 + wq16 + l16] = lred;
  }
}

// ---------------- combine: sum chunk partials, normalize, store (qt >= 16) ----------------
// 4 blocks per (b,qt): 16 q-rows each, for HBM-BW parallelism (1536 blocks).

__global__ __launch_bounds__(256)
void combine_kernel(const float* __restrict__ Pp, const float* __restrict__ Ls,
                    float* __restrict__ Out) {
  const int e    = (int)blockIdx.x >> 2;  // 8 batches x 48 qtiles
  const int qsub = (int)blockIdx.x & 3;
  const int b    = e & 7;
  const int qt   = 16 + (e >> 3);
  const int s0   = b * NSLOT + slot_base(qt);
  const int nch  = (qt >> 4) + 1;         // 2..4
  const int t = (int)threadIdx.x;
  #pragma unroll
  for (int j = 0; j < 2; ++j) {
    const int idx = j * 256 + t;          // 0..511 float4 (16q x 32)
    const int q   = qsub * 16 + (idx >> 5);
    const int d4  = idx & 31;
    float4 v = {0.f, 0.f, 0.f, 0.f};
    float  l = 0.f;
    for (int ch = 0; ch < nch; ++ch) {
      const float* pc = Pp + (size_t)(s0 + ch) * 8192 + (size_t)q * 128 + d4 * 4;
      float4 a = *(const float4*)pc;
      v.x += a.x; v.y += a.y; v.z += a.z; v.w += a.w;
      l += Ls[(size_t)(s0 + ch) * 64 + q];
    }
    const float inv = 1.0f / l;
    float4 r = {v.x * inv, v.y * inv, v.z * inv, v.w * inv};
    *(float4*)(Out + ((size_t)b * NSEQ + qt * 64 + q) * DIM + d4 * 4) = r;
  }
}

// ---------------- middle tier: round-1 64q-row kernel (16.8MB <= ws < 59MB) ----------------

template <bool MASK>
__device__ __forceinline__ void tile_compute(
    const bf16_t* __restrict__ kbuf, const bf16_t* __restrict__ vbuf,
    bf16_t* __restrict__ pl, const bf16x8 (&qf)[4],
    int l16, int quad, int wq, floatx4 (&acc)[8], float (&lsum)[4]) {
  floatx4 s[4];
  #pragma unroll
  for (int c4 = 0; c4 < 4; ++c4) s[c4] = (floatx4){0.f, 0.f, 0.f, 0.f};
  #pragma unroll
  for (int c4 = 0; c4 < 4; ++c4) {
    const bf16_t* krow = kbuf + (c4 * 16 + l16) * DIM;
    #pragma unroll
    for (int d = 0; d < 4; ++d) {
      bf16x8 kf = *(const bf16x8*)(krow + (((4 * d + quad) ^ l16) * 8));
      s[c4] = __builtin_amdgcn_mfma_f32_16x16x32_bf16(qf[d], kf, s[c4], 0, 0, 0);
    }
  }
  #pragma unroll
  for (int c4 = 0; c4 < 4; ++c4) {
    #pragma unroll
    for (int r = 0; r < 4; ++r) {
      float v = s[c4][r];
      if constexpr (MASK)
        v = (c4 * 16 + l16 <= wq + quad * 4 + r) ? v : -3.0e38f;
      float p = __builtin_amdgcn_exp2f(v);
      lsum[r] += p;
      pl[(quad * 4 + r) * 72 + c4 * 16 + l16] = (__bf16)p;
    }
  }
  asm volatile("s_waitcnt lgkmcnt(0)" ::: "memory");
  bf16x8 pfA = *(const bf16x8*)(pl + l16 * 72 + quad * 8);
  bf16x8 pfB = *(const bf16x8*)(pl + l16 * 72 + 32 + quad * 8);
  #pragma unroll
  for (int c = 0; c < 8; ++c) {
    const bf16_t* vrow = vbuf + (c * 16 + l16) * 64;
    bf16x8 vfA = *(const bf16x8*)(vrow + ((quad ^ (l16 & 7)) * 8));
    bf16x8 vfB = *(const bf16x8*)(vrow + (((quad + 4) ^ (l16 & 7)) * 8));
    acc[c] = __builtin_amdgcn_mfma_f32_16x16x32_bf16(pfA, vfA, acc[c], 0, 0, 0);
    acc[c] = __builtin_amdgcn_mfma_f32_16x16x32_bf16(pfB, vfB, acc[c], 0, 0, 0);
  }
}

__global__ __launch_bounds__(256)
void causal_attn_kernel(const float* __restrict__ Qf, const bf16_t* __restrict__ Kb,
                        const bf16_t* __restrict__ Vt, float* __restrict__ Out) {
  __shared__ __align__(16) bf16_t Kbuf[64 * DIM];
  __shared__ __align__(16) bf16_t Vbuf[DIM * 64];
  __shared__ __align__(16) bf16_t Pbuf[4][16 * 72];

  const int half = blockIdx.x >> 8;
  const int idx  = blockIdx.x & 255;
  const int b    = idx & 7;
  const int q32  = idx >> 3;
  const int qt64 = half ? q32 : 63 - q32;

  const int tid  = (int)threadIdx.x;
  const int wave = tid >> 6;
  const int lane = tid & 63;
  const int l16  = lane & 15;
  const int quad = lane >> 4;
  const int wq   = wave * 16;

  bf16x8 qf[4];
  {
    const float* qrow = Qf + ((size_t)b * NSEQ + qt64 * 64 + wq + l16) * DIM + quad * 8;
    #pragma unroll
    for (int d = 0; d < 4; ++d) qf[d] = ld8_f32s(qrow + 32 * d, SCALE_LOG2E);
  }

  const bf16_t* kg0 = Kb + ((size_t)b * NSEQ + 16 * wave) * DIM;
  const bf16_t* vg0 = Vt + ((size_t)b * DIM + 32 * wave) * NSEQ;
  int koff[4], voff[4];
  #pragma unroll
  for (int i = 0; i < 4; ++i) {
    const int krow = 4 * i + (lane >> 4);
    koff[i] = krow * DIM + (((lane & 15) ^ (krow & 15)) * 8);
    const int vrow = 8 * i + (lane >> 3);
    voff[i] = vrow * NSEQ + (((lane & 7) ^ ((lane >> 3) & 7)) * 8);
  }
  bf16_t* kl = Kbuf + 16 * wave * DIM;
  bf16_t* vl = Vbuf + 32 * wave * 64;
  bf16_t* pl = Pbuf[wave];

  floatx4 acc[8];
  #pragma unroll
  for (int c = 0; c < 8; ++c) acc[c] = (floatx4){0.f, 0.f, 0.f, 0.f};
  float lsum[4] = {0.f, 0.f, 0.f, 0.f};

  const int nk = qt64 + 1;
  for (int kt = 0; kt < nk - 1; ++kt) {
    const int kb = kt * 64;
    #pragma unroll
    for (int i = 0; i < 4; ++i) gld16(kl + i * 512, kg0 + (size_t)kb * DIM + koff[i]);
    #pragma unroll
    for (int i = 0; i < 4; ++i) gld16(vl + i * 512, vg0 + kb + voff[i]);
    __syncthreads();
    tile_compute<false>(Kbuf, Vbuf, pl, qf, l16, quad, wq, acc, lsum);
    __syncthreads();
  }
  {
    const int kb = (nk - 1) * 64;
    #pragma unroll
    for (int i = 0; i < 4; ++i) gld16(kl + i * 512, kg0 + (size_t)kb * DIM + koff[i]);
    #pragma unroll
    for (int i = 0; i < 4; ++i) gld16(vl + i * 512, vg0 + kb + voff[i]);
    __syncthreads();
    tile_compute<true>(Kbuf, Vbuf, pl, qf, l16, quad, wq, acc, lsum);
  }

  float inv_l[4];
  #pragma unroll
  for (int r = 0; r < 4; ++r) {
    float s = lsum[r];
    #pragma unroll
    for (int off = 1; off < 16; off <<= 1) s += __shfl_xor(s, off, 64);
    inv_l[r] = 1.0f / s;
  }
  float* orow = Out + ((size_t)b * NSEQ + qt64 * 64 + wq + quad * 4) * DIM + l16;
  #pragma unroll
  for (int c = 0; c < 8; ++c) {
    #pragma unroll
    for (int r = 0; r < 4; ++r)
      orow[(size_t)r * DIM + c * 16] = acc[c][r] * inv_l[r];
  }
}

// ---------------- fallback (no workspace): fp32 direct ----------------

__global__ __launch_bounds__(256)
void causal_attn_fb(const float* __restrict__ Qf, const float* __restrict__ Kf,
                    const float* __restrict__ Vf, float* __restrict__ Out) {
  __shared__ bf16_t p_lds[4][16 * 72];
  const int bid = blockIdx.x, t = bid >> 3, b = bid & 7;
  const int tid = (int)threadIdx.x, wave = tid >> 6, lane = tid & 63;
  const int l16 = lane & 15, quad = lane >> 4;
  const int qtile = (wave < 2) ? t : (127 - t);
  const int q_base = qtile * 32 + (wave & 1) * 16;

  bf16x8 qf[4];
  const float* qrow = Qf + ((size_t)b * NSEQ + q_base + l16) * DIM + quad * 8;
  #pragma unroll
  for (int d = 0; d < 4; ++d) qf[d] = ld8_f32s(qrow + 32 * d, SCALE_LOG2E);

  floatx4 acc[8];
  #pragma unroll
  for (int c = 0; c < 8; ++c) acc[c] = (floatx4){0.f, 0.f, 0.f, 0.f};
  float lsum[4] = {0.f, 0.f, 0.f, 0.f};
  bf16_t* pl = p_lds[wave];
  const int ntiles = (q_base + 16 + 63) >> 6;

  for (int kt = 0; kt < ntiles; ++kt) {
    const int kb = kt * 64;
    floatx4 s[4];
    #pragma unroll
    for (int c4 = 0; c4 < 4; ++c4) s[c4] = (floatx4){0.f, 0.f, 0.f, 0.f};
    const float* kbase = Kf + ((size_t)b * NSEQ + kb + l16) * DIM + quad * 8;
    #pragma unroll
    for (int c4 = 0; c4 < 4; ++c4) {
      #pragma unroll
      for (int d = 0; d < 4; ++d) {
        bf16x8 kf = ld8_f32s(kbase + (size_t)c4 * 16 * DIM + 32 * d, 1.0f);
        s[c4] = __builtin_amdgcn_mfma_f32_16x16x32_bf16(qf[d], kf, s[c4], 0, 0, 0);
      }
    }
    #pragma unroll
    for (int c4 = 0; c4 < 4; ++c4) {
      #pragma unroll
      for (int r = 0; r < 4; ++r) {
        float v = s[c4][r];
        const int qi = q_base + quad * 4 + r;
        v = (kb + c4 * 16 + l16 <= qi) ? v : -3.0e38f;
        float p = __builtin_amdgcn_exp2f(v);
        lsum[r] += p;
        pl[(quad * 4 + r) * 72 + c4 * 16 + l16] = (__bf16)p;
      }
    }
    asm volatile("s_waitcnt lgkmcnt(0)" ::: "memory");
    bf16x8 pfA = *(const bf16x8*)(pl + l16 * 72 + quad * 8);
    bf16x8 pfB = *(const bf16x8*)(pl + l16 * 72 + 32 + quad * 8);
    const float* vb = Vf + ((size_t)b * NSEQ + kb) * DIM;
    #pragma unroll
    for (int c = 0; c < 8; ++c) {
      bf16x8 vfA, vfB;
      #pragma unroll
      for (int j = 0; j < 8; ++j) {
        vfA[j] = (__bf16)vb[(size_t)(quad * 8 + j) * DIM + c * 16 + l16];
        vfB[j] = (__bf16)vb[(size_t)(32 + quad * 8 + j) * DIM + c * 16 + l16];
      }
      acc[c] = __builtin_amdgcn_mfma_f32_16x16x32_bf16(pfA, vfA, acc[c], 0, 0, 0);
      acc[c] = __builtin_amdgcn_mfma_f32_16x16x32_bf16(pfB, vfB, acc[c], 0, 0, 0);
    }
  }
  float inv_l[4];
  #pragma unroll
  for (int r = 0; r < 4; ++r) {
    float s = lsum[r];
    #pragma unroll
    for (int off = 1; off < 16; off <<= 1) s += __shfl_xor(s, off, 64);
    inv_l[r] = 1.0f / s;
  }
  float* orow = Out + ((size_t)b * NSEQ + q_base + quad * 4) * DIM + l16;
  #pragma unroll
  for (int c = 0; c < 8; ++c) {
    #pragma unroll
    for (int r = 0; r < 4; ++r)
      orow[(size_t)r * DIM + c * 16] = acc[c][r] * inv_l[r];
  }
}

extern "C" void kernel_launch(void* const* d_in, const int* in_sizes, int n_in,
                              void* d_out, int out_size, void* d_ws, size_t ws_size,
                              hipStream_t stream) {
  const float* Q = (const float*)d_in[0];
  const float* K = (const float*)d_in[1];
  const float* V = (const float*)d_in[2];
  float* Out = (float*)d_out;
  (void)in_sizes; (void)n_in; (void)out_size;

  dim3 block(256);
  if (ws_size >= WS_SPLITK) {
    bf16_t* Kb = (bf16_t*)d_ws;
    bf16_t* Vt = Kb + NELEM;
    float*  Pp = (float*)((char*)d_ws + WS_NEED);
    float*  Ls = Pp + (size_t)BATCH * NSLOT * 8192;
    prep_kernel<<<dim3(2048), block, 0, stream>>>(K, V, Kb, Vt);
    causal_attn_splitk<<<dim3(BATCH * NSLOT), block, 0, stream>>>(Q, Kb, Vt, Out, Pp, Ls);
    combine_kernel<<<dim3(BATCH * 48 * 4), block, 0, stream>>>(Pp, Ls, Out);
  } else if (ws_size >= WS_NEED) {
    bf16_t* Kb = (bf16_t*)d_ws;
    bf16_t* Vt = Kb + NELEM;
    prep_kernel<<<dim3(2048), block, 0, stream>>>(K, V, Kb, Vt);
    causal_attn_kernel<<<dim3(512), block, 0, stream>>>(Q, Kb, Vt, Out);
  } else {
    causal_attn_fb<<<dim3(512), block, 0, stream>>>(Q, K, V, Out);
  }
}

// Round 14
// 151.778 us; speedup vs baseline: 2.3616x; 1.0074x over previous
//
#include <hip/hip_runtime.h>
#include <hip/hip_bf16.h>

typedef __bf16 bf16_t;
typedef __attribute__((ext_vector_type(8))) __bf16 bf16x8;
typedef __attribute__((ext_vector_type(4))) __bf16 bf16x4;
typedef __attribute__((ext_vector_type(4))) float floatx4;

// B=8, N=4096, D=CV=128. fp32 in/out; bf16 MFMA compute, fp32 accumulate.
static constexpr int NSEQ = 4096;
static constexpr int DIM  = 128;
static constexpr int BATCH = 8;
static constexpr size_t NELEM = (size_t)BATCH * NSEQ * DIM;
static constexpr size_t WS_NEED = 2 * NELEM * sizeof(bf16_t);   // Kb + Vt = 16 MiB

// ---- split-K over 64-row q-tiles (64 per batch), 64-key tiles, band 32 ----
// nch = qt/32 + 1 (1 or 2); NSLOT = 32 + 64 = 96/batch; grid 768 (= 3 blk/CU exactly).
static constexpr int NSLOT = 96;
static constexpr size_t WS_SPLITK =
    WS_NEED + (size_t)BATCH * NSLOT * (8192 + 64) * sizeof(float);   // ~42.1 MB

// 1/sqrt(128) * log2(e); folded into Q so the inner loop is bare exp2.
static constexpr float SCALE_LOG2E = 0.08838834764831845f * 1.4426950408889634f;

// S(qt) = slots before q-tile qt, band 32: g=qt>>5 (0|1) -> qt + (qt-32)*g
__device__ __forceinline__ int slot_base(int qt) {
  int g = qt >> 5;
  return qt + (qt - 32) * g;
}

// async global->LDS, 16B per lane; LDS dest = wave-uniform base + lane*16
__device__ __forceinline__ void gld16(bf16_t* l, const bf16_t* g) {
  __builtin_amdgcn_global_load_lds(
      (const __attribute__((address_space(1))) unsigned int*)g,
      (__attribute__((address_space(3))) unsigned int*)l, 16, 0, 0);
}

__device__ __forceinline__ bf16x8 ld8_f32s(const float* p, float s) {
  float4 a = *(const float4*)p;
  float4 b = *(const float4*)(p + 4);
  bf16x8 r = {(__bf16)(a.x * s), (__bf16)(a.y * s), (__bf16)(a.z * s), (__bf16)(a.w * s),
              (__bf16)(b.x * s), (__bf16)(b.y * s), (__bf16)(b.z * s), (__bf16)(b.w * s)};
  return r;
}

// ---------------- prep: K fp32->bf16 (16B stores), V fp32 -> Vt bf16 [B][dim][key] ----------------

__global__ __launch_bounds__(256)
void prep_kernel(const float* __restrict__ K, const float* __restrict__ V,
                 bf16_t* __restrict__ Kb, bf16_t* __restrict__ Vt) {
  __shared__ bf16_t ldsT[128 * 66];       // [dim][key], stride 66 to spread banks
  const int bid = blockIdx.x;
  if (bid < 1536) {                       // K convert, grid-stride, 16B stores
    const size_t n8 = NELEM / 8;
    for (size_t i = (size_t)bid * 256 + threadIdx.x; i < n8; i += (size_t)1536 * 256) {
      float4 a = ((const float4*)K)[2 * i];
      float4 c = ((const float4*)K)[2 * i + 1];
      bf16x8 kv = {(__bf16)a.x, (__bf16)a.y, (__bf16)a.z, (__bf16)a.w,
                   (__bf16)c.x, (__bf16)c.y, (__bf16)c.z, (__bf16)c.w};
      ((bf16x8*)Kb)[i] = kv;
    }
  } else {                                // V transpose+convert, one 64-key tile/block
    const int id = bid - 1536;            // 0..511
    const int b  = id & 7;
    const int kt = id >> 3;               // 0..63
    const float* src = V + ((size_t)(b * NSEQ + kt * 64)) * DIM;
    #pragma unroll
    for (int it = 0; it < 8; ++it) {
      const int idx = it * 256 + (int)threadIdx.x;   // 0..2047 float4
      const int k = idx >> 5, c4 = idx & 31;
      float4 v = ((const float4*)src)[idx];
      ldsT[(c4 * 4 + 0) * 66 + k] = (__bf16)v.x;
      ldsT[(c4 * 4 + 1) * 66 + k] = (__bf16)v.y;
      ldsT[(c4 * 4 + 2) * 66 + k] = (__bf16)v.z;
      ldsT[(c4 * 4 + 3) * 66 + k] = (__bf16)v.w;
    }
    __syncthreads();
    #pragma unroll
    for (int it = 0; it < 4; ++it) {
      const int task = it * 256 + (int)threadIdx.x;  // 0..1023
      const int d = task >> 3, kg = task & 7;
      bf16x8 o;
      #pragma unroll
      for (int j = 0; j < 8; ++j) o[j] = ldsT[d * 66 + kg * 8 + j];
      *(bf16x8*)(Vt + ((size_t)b * DIM + d) * NSEQ + kt * 64 + kg * 8) = o;
    }
  }
}

// ---------------- per-tile compute: 16q x 64k per wave, swapped QK^T, in-reg P ----------------
// K staged with row permutation pi so each lane's QK^T outputs ARE its PV A-fragment
// (keys 32h+8quad+4cc+r, lane-local); lane's q-column is l16. Verbatim best (r8/r13).

template <bool MASK>
__device__ __forceinline__ void tile16(
    const bf16_t* __restrict__ kbuf, const bf16_t* __restrict__ vbuf,
    const bf16x8 (&qf)[4], int l16, int quad, int wq16,
    floatx4 (&acc)[8], float& lsum) {
  #pragma unroll
  for (int h = 0; h < 2; ++h) {           // key half: 32h .. 32h+31
    float pr[8];                          // lane-local P values, keys 32h+8quad+{0..7}
    #pragma unroll
    for (int cc = 0; cc < 2; ++cc) {
      const int c4 = 2 * h + cc;
      floatx4 sv = {0.f, 0.f, 0.f, 0.f};
      const bf16_t* krow = kbuf + (c4 * 16 + l16) * DIM;
      #pragma unroll
      for (int d = 0; d < 4; ++d) {
        bf16x8 kf = *(const bf16x8*)(krow + (((4 * d + quad) ^ l16) * 8));
        sv = __builtin_amdgcn_mfma_f32_16x16x32_bf16(kf, qf[d], sv, 0, 0, 0);
      }
      #pragma unroll
      for (int r = 0; r < 4; ++r) {
        float v = sv[r];
        if constexpr (MASK) {
          const int key = 32 * h + 8 * quad + 4 * cc + r;        // pi-mapped key
          v = (key <= wq16 + l16) ? v : -3.0e38f;                // exp2 -> 0
        }
        float p = __builtin_amdgcn_exp2f(v);
        lsum += p;
        pr[4 * cc + r] = p;
      }
    }
    bf16x8 pf;
    #pragma unroll
    for (int j = 0; j < 8; ++j) pf[j] = (__bf16)pr[j];
    // ---- O += P(:,32h..32h+31) * V(32h..32h+31,:) ----
    __builtin_amdgcn_s_setprio(1);
    #pragma unroll
    for (int c = 0; c < 8; ++c) {
      const bf16_t* vrow = vbuf + (c * 16 + l16) * 64;
      bf16x8 vf = *(const bf16x8*)(vrow + (((quad + 4 * h) ^ (l16 & 7)) * 8));
      acc[c] = __builtin_amdgcn_mfma_f32_16x16x32_bf16(pf, vf, acc[c], 0, 0, 0);
    }
    __builtin_amdgcn_s_setprio(0);
  }
}

// ---------------- split-K attention: K-dbuf LDS + V reg-staged (48 KB), 3 blk/CU ----------------
// Inner loop verbatim round-8/13 (best measured). Band-32 decomposition: grid 768
// (exactly co-resident), only qt>=32 splits (2 strided chunks) -> half the partials.

__global__ __launch_bounds__(256, 3)
void causal_attn_splitk(const float* __restrict__ Qf, const bf16_t* __restrict__ Kb,
                        const bf16_t* __restrict__ Vt, float* __restrict__ Out,
                        float* __restrict__ Pp, float* __restrict__ Ls) {
  __shared__ __align__(16) bf16_t Kds[2][64 * DIM];   // 2 x 16 KB
  __shared__ __align__(16) bf16_t Vds[DIM * 64];      // 16 KB -> 48 KB total

  const int b = (int)blockIdx.x & 7;                  // batch -> XCD (L2 affinity)
  const int s = (NSLOT - 1) - ((int)blockIdx.x >> 3); // longest chunks first
  int qt, cch;
  if (s < 32) { qt = s; cch = 0; }                    // band 0: 1 chunk
  else { const int u = s - 32; qt = 32 + (u >> 1); cch = u & 1; }  // band 1: 2 chunks
  const int ntot = qt + 1;                            // 64-key tiles for this q-tile
  const int nch  = (qt >> 5) + 1;
  const int nt_c = (ntot - 1 - cch) / nch + 1;        // tiles in this (strided) chunk
  const int nmask = (cch + (nt_c - 1) * nch == qt) ? 1 : 0;
  const int nfull = nt_c - nmask;

  const int tid  = (int)threadIdx.x;
  const int wave = tid >> 6;
  const int lane = tid & 63;
  const int l16  = lane & 15;
  const int quad = lane >> 4;
  const int wq16 = wave * 16;                         // wave's 16 q-rows within tile

  // Q fragments (B-operand): lane(l16,quad) = Q[q=wq16+l16][dims 32d+8quad..+8]
  bf16x8 qf[4];
  {
    const float* qrow =
        Qf + ((size_t)b * NSEQ + qt * 64 + wq16 + l16) * DIM + quad * 8;
    #pragma unroll
    for (int d = 0; d < 4; ++d) qf[d] = ld8_f32s(qrow + 32 * d, SCALE_LOG2E);
  }

  // staging: K rows permuted by pi, dim chunks XOR'd on SOURCE (gld16, linear dest).
  // V: prologue via gld16 (source-XOR); steady-state via regs: LINEAR global source,
  // XOR applied on the ds_write DEST. Readers unchanged.
  const bf16_t* kg = Kb + (size_t)b * NSEQ * DIM;
  const bf16_t* vg = Vt + ((size_t)b * DIM + 32 * wave) * NSEQ;
  int koff[4], voff[4], vsrc[4], vdst[4];
  #pragma unroll
  for (int i = 0; i < 4; ++i) {
    const int p    = 16 * wave + 4 * i + quad;
    const int srow = 32 * (wave >> 1) + 8 * i + 4 * (wave & 1) + quad;  // pi(p)
    koff[i] = srow * DIM + ((l16 ^ (p & 15)) * 8);
    const int vrow = 8 * i + (lane >> 3);              // 0..31
    voff[i] = vrow * NSEQ + (((lane & 7) ^ (vrow & 7)) * 8);            // gld16 source
    vsrc[i] = vrow * NSEQ + (lane & 7) * 8;                             // reg source
    vdst[i] = (32 * wave + vrow) * 64 + (((lane & 7) ^ (vrow & 7)) * 8);// ds_write dest
  }

  floatx4 acc[8];
  #pragma unroll
  for (int c = 0; c < 8; ++c) acc[c] = (floatx4){0.f, 0.f, 0.f, 0.f};
  float lsum = 0.f;

  // prologue: stage tile cch (K -> buf 0, V -> single buffer), both via gld16
  {
    const size_t kb0 = (size_t)cch * 64;
    bf16_t* kl = &Kds[0][wave * 2048];
    bf16_t* vl = &Vds[wave * 2048];
    #pragma unroll
    for (int i = 0; i < 4; ++i) {
      gld16(kl + i * 512, kg + kb0 * DIM + koff[i]);
      gld16(vl + i * 512, vg + kb0 + voff[i]);
    }
  }
  __syncthreads();                        // drains vmcnt -> tile 0 ready

  bf16x8 vreg[4];
  int t = cch;
  for (int it = 0; it < nt_c; ++it, t += nch) {
    const int cur = it & 1;
    const bool more = (it + 1 < nt_c);    // block-uniform
    const size_t kbn = (size_t)(t + nch) * 64;
    if (more) {                           // K prefetch (LDS-direct) + V load-to-reg,
      bf16_t* kl = &Kds[cur ^ 1][wave * 2048];       // both hidden under compute
      #pragma unroll
      for (int i = 0; i < 4; ++i) gld16(kl + i * 512, kg + kbn * DIM + koff[i]);
      #pragma unroll
      for (int i = 0; i < 4; ++i) vreg[i] = *(const bf16x8*)(vg + kbn + vsrc[i]);
    }
    __builtin_amdgcn_sched_barrier(0);    // loads issue before compute
    if (it < nfull)
      tile16<false>(Kds[cur], Vds, qf, l16, quad, wq16, acc, lsum);
    else
      tile16<true>(Kds[cur], Vds, qf, l16, quad, wq16, acc, lsum);
    __builtin_amdgcn_sched_barrier(0);
    __builtin_amdgcn_s_barrier();         // all waves done reading Vds / Kds[cur]
    if (more) {
      // ds_write forces vmcnt wait on V regs (youngest) -> older K gld16 also retired
      #pragma unroll
      for (int i = 0; i < 4; ++i) *(bf16x8*)(&Vds[vdst[i]]) = vreg[i];
      asm volatile("s_waitcnt lgkmcnt(0)" ::: "memory");  // writes visible pre-barrier
      __builtin_amdgcn_sched_barrier(0);
      __builtin_amdgcn_s_barrier();       // staged tile visible to all waves
    }
  }

  // ---- l-reduction across quads (q = l16 per wave) ----
  float lred = lsum;
  lred += __shfl_xor(lred, 16, 64);
  lred += __shfl_xor(lred, 32, 64);

  if (nch == 1) {                                     // single chunk: direct output
    float invl[4];
    #pragma unroll
    for (int r = 0; r < 4; ++r)
      invl[r] = 1.0f / __shfl(lred, quad * 4 + r, 64);
    float* orow =
        Out + ((size_t)b * NSEQ + qt * 64 + wq16 + quad * 4) * DIM + l16;
    #pragma unroll
    for (int c = 0; c < 8; ++c)
      #pragma unroll
      for (int r = 0; r < 4; ++r)
        orow[(size_t)r * DIM + c * 16] = acc[c][r] * invl[r];
  } else {                                            // unnormalized partials
    const int slot = b * NSLOT + slot_base(qt) + cch;
    float* pb = Pp + (size_t)slot * 8192 +
                ((size_t)(wq16 + quad * 4)) * 128 + l16;
    #pragma unroll
    for (int c = 0; c < 8; ++c)
      #pragma unroll
      for (int r = 0; r < 4; ++r)
        pb[(size_t)r * 128 + c * 16] = acc[c][r];
    if (quad == 0)
      Ls[(size_t)slot * 64 + wq16 + l16] = lred;
  }
}

// ---------------- combine: sum 2 chunk partials, normalize, store (qt >= 32) ----------------
// 4 blocks per (b,qt): 16 q-rows each (1024 blocks).

__global__ __launch_bounds__(256)
void combine_kernel(const float* __restrict__ Pp, const float* __restrict__ Ls,
                    float* __restrict__ Out) {
  const int e    = (int)blockIdx.x >> 2;  // 8 batches x 32 qtiles
  const int qsub = (int)blockIdx.x & 3;
  const int b    = e & 7;
  const int qt   = 32 + (e >> 3);
  const int s0   = b * NSLOT + slot_base(qt);
  const int nch  = (qt >> 5) + 1;         // == 2
  const int t = (int)threadIdx.x;
  #pragma unroll
  for (int j = 0; j < 2; ++j) {
    const int idx = j * 256 + t;          // 0..511 float4 (16q x 32)
    const int q   = qsub * 16 + (idx >> 5);
    const int d4  = idx & 31;
    float4 v = {0.f, 0.f, 0.f, 0.f};
    float  l = 0.f;
    for (int ch = 0; ch < nch; ++ch) {
      const float* pc = Pp + (size_t)(s0 + ch) * 8192 + (size_t)q * 128 + d4 * 4;
      float4 a = *(const float4*)pc;
      v.x += a.x; v.y += a.y; v.z += a.z; v.w += a.w;
      l += Ls[(size_t)(s0 + ch) * 64 + q];
    }
    const float inv = 1.0f / l;
    float4 r = {v.x * inv, v.y * inv, v.z * inv, v.w * inv};
    *(float4*)(Out + ((size_t)b * NSEQ + qt * 64 + q) * DIM + d4 * 4) = r;
  }
}

// ---------------- middle tier: round-1 64q-row kernel (16.8MB <= ws < 42MB) ----------------

template <bool MASK>
__device__ __forceinline__ void tile_compute(
    const bf16_t* __restrict__ kbuf, const bf16_t* __restrict__ vbuf,
    bf16_t* __restrict__ pl, const bf16x8 (&qf)[4],
    int l16, int quad, int wq, floatx4 (&acc)[8], float (&lsum)[4]) {
  floatx4 s[4];
  #pragma unroll
  for (int c4 = 0; c4 < 4; ++c4) s[c4] = (floatx4){0.f, 0.f, 0.f, 0.f};
  #pragma unroll
  for (int c4 = 0; c4 < 4; ++c4) {
    const bf16_t* krow = kbuf + (c4 * 16 + l16) * DIM;
    #pragma unroll
    for (int d = 0; d < 4; ++d) {
      bf16x8 kf = *(const bf16x8*)(krow + (((4 * d + quad) ^ l16) * 8));
      s[c4] = __builtin_amdgcn_mfma_f32_16x16x32_bf16(qf[d], kf, s[c4], 0, 0, 0);
    }
  }
  #pragma unroll
  for (int c4 = 0; c4 < 4; ++c4) {
    #pragma unroll
    for (int r = 0; r < 4; ++r) {
      float v = s[c4][r];
      if constexpr (MASK)
        v = (c4 * 16 + l16 <= wq + quad * 4 + r) ? v : -3.0e38f;
      float p = __builtin_amdgcn_exp2f(v);
      lsum[r] += p;
      pl[(quad * 4 + r) * 72 + c4 * 16 + l16] = (__bf16)p;
    }
  }
  asm volatile("s_waitcnt lgkmcnt(0)" ::: "memory");
  bf16x8 pfA = *(const bf16x8*)(pl + l16 * 72 + quad * 8);
  bf16x8 pfB = *(const bf16x8*)(pl + l16 * 72 + 32 + quad * 8);
  #pragma unroll
  for (int c = 0; c < 8; ++c) {
    const bf16_t* vrow = vbuf + (c * 16 + l16) * 64;
    bf16x8 vfA = *(const bf16x8*)(vrow + ((quad ^ (l16 & 7)) * 8));
    bf16x8 vfB = *(const bf16x8*)(vrow + (((quad + 4) ^ (l16 & 7)) * 8));
    acc[c] = __builtin_amdgcn_mfma_f32_16x16x32_bf16(pfA, vfA, acc[c], 0, 0, 0);
    acc[c] = __builtin_amdgcn_mfma_f32_16x16x32_bf16(pfB, vfB, acc[c], 0, 0, 0);
  }
}

__global__ __launch_bounds__(256)
void causal_attn_kernel(const float* __restrict__ Qf, const bf16_t* __restrict__ Kb,
                        const bf16_t* __restrict__ Vt, float* __restrict__ Out) {
  __shared__ __align__(16) bf16_t Kbuf[64 * DIM];
  __shared__ __align__(16) bf16_t Vbuf[DIM * 64];
  __shared__ __align__(16) bf16_t Pbuf[4][16 * 72];

  const int half = blockIdx.x >> 8;
  const int idx  = blockIdx.x & 255;
  const int b    = idx & 7;
  const int q32  = idx >> 3;
  const int qt64 = half ? q32 : 63 - q32;

  const int tid  = (int)threadIdx.x;
  const int wave = tid >> 6;
  const int lane = tid & 63;
  const int l16  = lane & 15;
  const int quad = lane >> 4;
  const int wq   = wave * 16;

  bf16x8 qf[4];
  {
    const float* qrow = Qf + ((size_t)b * NSEQ + qt64 * 64 + wq + l16) * DIM + quad * 8;
    #pragma unroll
    for (int d = 0; d < 4; ++d) qf[d] = ld8_f32s(qrow + 32 * d, SCALE_LOG2E);
  }

  const bf16_t* kg0 = Kb + ((size_t)b * NSEQ + 16 * wave) * DIM;
  const bf16_t* vg0 = Vt + ((size_t)b * DIM + 32 * wave) * NSEQ;
  int koff[4], voff[4];
  #pragma unroll
  for (int i = 0; i < 4; ++i) {
    const int krow = 4 * i + (lane >> 4);
    koff[i] = krow * DIM + (((lane & 15) ^ (krow & 15)) * 8);
    const int vrow = 8 * i + (lane >> 3);
    voff[i] = vrow * NSEQ + (((lane & 7) ^ ((lane >> 3) & 7)) * 8);
  }
  bf16_t* kl = Kbuf + 16 * wave * DIM;
  bf16_t* vl = Vbuf + 32 * wave * 64;
  bf16_t* pl = Pbuf[wave];

  floatx4 acc[8];
  #pragma unroll
  for (int c = 0; c < 8; ++c) acc[c] = (floatx4){0.f, 0.f, 0.f, 0.f};
  float lsum[4] = {0.f, 0.f, 0.f, 0.f};

  const int nk = qt64 + 1;
  for (int kt = 0; kt < nk - 1; ++kt) {
    const int kb = kt * 64;
    #pragma unroll
    for (int i = 0; i < 4; ++i) gld16(kl + i * 512, kg0 + (size_t)kb * DIM + koff[i]);
    #pragma unroll
    for (int i = 0; i < 4; ++i) gld16(vl + i * 512, vg0 + kb + voff[i]);
    __syncthreads();
    tile_compute<false>(Kbuf, Vbuf, pl, qf, l16, quad, wq, acc, lsum);
    __syncthreads();
  }
  {
    const int kb = (nk - 1) * 64;
    #pragma unroll
    for (int i = 0; i < 4; ++i) gld16(kl + i * 512, kg0 + (size_t)kb * DIM + koff[i]);
    #pragma unroll
    for (int i = 0; i < 4; ++i) gld16(vl + i * 512, vg0 + kb + voff[i]);
    __syncthreads();
    tile_compute<true>(Kbuf, Vbuf, pl, qf, l16, quad, wq, acc, lsum);
  }

  float inv_l[4];
  #pragma unroll
  for (int r = 0; r < 4; ++r) {
    float s = lsum[r];
    #pragma unroll
    for (int off = 1; off < 16; off <<= 1) s += __shfl_xor(s, off, 64);
    inv_l[r] = 1.0f / s;
  }
  float* orow = Out + ((size_t)b * NSEQ + qt64 * 64 + wq + quad * 4) * DIM + l16;
  #pragma unroll
  for (int c = 0; c < 8; ++c) {
    #pragma unroll
    for (int r = 0; r < 4; ++r)
      orow[(size_t)r * DIM + c * 16] = acc[c][r] * inv_l[r];
  }
}

// ---------------- fallback (no workspace): fp32 direct ----------------

__global__ __launch_bounds__(256)
void causal_attn_fb(const float* __restrict__ Qf, const float* __restrict__ Kf,
                    const float* __restrict__ Vf, float* __restrict__ Out) {
  __shared__ bf16_t p_lds[4][16 * 72];
  const int bid = blockIdx.x, t = bid >> 3, b = bid & 7;
  const int tid = (int)threadIdx.x, wave = tid >> 6, lane = tid & 63;
  const int l16 = lane & 15, quad = lane >> 4;
  const int qtile = (wave < 2) ? t : (127 - t);
  const int q_base = qtile * 32 + (wave & 1) * 16;

  bf16x8 qf[4];
  const float* qrow = Qf + ((size_t)b * NSEQ + q_base + l16) * DIM + quad * 8;
  #pragma unroll
  for (int d = 0; d < 4; ++d) qf[d] = ld8_f32s(qrow + 32 * d, SCALE_LOG2E);

  floatx4 acc[8];
  #pragma unroll
  for (int c = 0; c < 8; ++c) acc[c] = (floatx4){0.f, 0.f, 0.f, 0.f};
  float lsum[4] = {0.f, 0.f, 0.f, 0.f};
  bf16_t* pl = p_lds[wave];
  const int ntiles = (q_base + 16 + 63) >> 6;

  for (int kt = 0; kt < ntiles; ++kt) {
    const int kb = kt * 64;
    floatx4 s[4];
    #pragma unroll
    for (int c4 = 0; c4 < 4; ++c4) s[c4] = (floatx4){0.f, 0.f, 0.f, 0.f};
    const float* kbase = Kf + ((size_t)b * NSEQ + kb + l16) * DIM + quad * 8;
    #pragma unroll
    for (int c4 = 0; c4 < 4; ++c4) {
      #pragma unroll
      for (int d = 0; d < 4; ++d) {
        bf16x8 kf = ld8_f32s(kbase + (size_t)c4 * 16 * DIM + 32 * d, 1.0f);
        s[c4] = __builtin_amdgcn_mfma_f32_16x16x32_bf16(qf[d], kf, s[c4], 0, 0, 0);
      }
    }
    #pragma unroll
    for (int c4 = 0; c4 < 4; ++c4) {
      #pragma unroll
      for (int r = 0; r < 4; ++r) {
        float v = s[c4][r];
        const int qi = q_base + quad * 4 + r;
        v = (kb + c4 * 16 + l16 <= qi) ? v : -3.0e38f;
        float p = __builtin_amdgcn_exp2f(v);
        lsum[r] += p;
        pl[(quad * 4 + r) * 72 + c4 * 16 + l16] = (__bf16)p;
      }
    }
    asm volatile("s_waitcnt lgkmcnt(0)" ::: "memory");
    bf16x8 pfA = *(const bf16x8*)(pl + l16 * 72 + quad * 8);
    bf16x8 pfB = *(const bf16x8*)(pl + l16 * 72 + 32 + quad * 8);
    const float* vb = Vf + ((size_t)b * NSEQ + kb) * DIM;
    #pragma unroll
    for (int c = 0; c < 8; ++c) {
      bf16x8 vfA, vfB;
      #pragma unroll
      for (int j = 0; j < 8; ++j) {
        vfA[j] = (__bf16)vb[(size_t)(quad * 8 + j) * DIM + c * 16 + l16];
        vfB[j] = (__bf16)vb[(size_t)(32 + quad * 8 + j) * DIM + c * 16 + l16];
      }
      acc[c] = __builtin_amdgcn_mfma_f32_16x16x32_bf16(pfA, vfA, acc[c], 0, 0, 0);
      acc[c] = __builtin_amdgcn_mfma_f32_16x16x32_bf16(pfB, vfB, acc[c], 0, 0, 0);
    }
  }
  float inv_l[4];
  #pragma unroll
  for (int r = 0; r < 4; ++r) {
    float s = lsum[r];
    #pragma unroll
    for (int off = 1; off < 16; off <<= 1) s += __shfl_xor(s, off, 64);
    inv_l[r] = 1.0f / s;
  }
  float* orow = Out + ((size_t)b * NSEQ + q_base + quad * 4) * DIM + l16;
  #pragma unroll
  for (int c = 0; c < 8; ++c) {
    #pragma unroll
    for (int r = 0; r < 4; ++r)
      orow[(size_t)r * DIM + c * 16] = acc[c][r] * inv_l[r];
  }
}

extern "C" void kernel_launch(void* const* d_in, const int* in_sizes, int n_in,
                              void* d_out, int out_size, void* d_ws, size_t ws_size,
                              hipStream_t stream) {
  const float* Q = (const float*)d_in[0];
  const float* K = (const float*)d_in[1];
  const float* V = (const float*)d_in[2];
  float* Out = (float*)d_out;
  (void)in_sizes; (void)n_in; (void)out_size;

  dim3 block(256);
  if (ws_size >= WS_SPLITK) {
    bf16_t* Kb = (bf16_t*)d_ws;
    bf16_t* Vt = Kb + NELEM;
    float*  Pp = (float*)((char*)d_ws + WS_NEED);
    float*  Ls = Pp + (size_t)BATCH * NSLOT * 8192;
    prep_kernel<<<dim3(2048), block, 0, stream>>>(K, V, Kb, Vt);
    causal_attn_splitk<<<dim3(BATCH * NSLOT), block, 0, stream>>>(Q, Kb, Vt, Out, Pp, Ls);
    combine_kernel<<<dim3(BATCH * 32 * 4), block, 0, stream>>>(Pp, Ls, Out);
  } else if (ws_size >= WS_NEED) {
    bf16_t* Kb = (bf16_t*)d_ws;
    bf16_t* Vt = Kb + NELEM;
    prep_kernel<<<dim3(2048), block, 0, stream>>>(K, V, Kb, Vt);
    causal_attn_kernel<<<dim3(512), block, 0, stream>>>(Q, Kb, Vt, Out);
  } else {
    causal_attn_fb<<<dim3(512), block, 0, stream>>>(Q, K, V, Out);
  }
}

// Round 15
// 147.170 us; speedup vs baseline: 2.4355x; 1.0313x over previous
//
#include <hip/hip_runtime.h>
#include <hip/hip_bf16.h>

typedef __bf16 bf16_t;
typedef __attribute__((ext_vector_type(8))) __bf16 bf16x8;
typedef __attribute__((ext_vector_type(4))) __bf16 bf16x4;
typedef __attribute__((ext_vector_type(4))) float floatx4;

// B=8, N=4096, D=CV=128. fp32 in/out; bf16 MFMA compute, fp32 accumulate.
static constexpr int NSEQ = 4096;
static constexpr int DIM  = 128;
static constexpr int BATCH = 8;
static constexpr size_t NELEM = (size_t)BATCH * NSEQ * DIM;
static constexpr size_t WS_NEED = 2 * NELEM * sizeof(bf16_t);   // Kb + Vt = 16 MiB

// ---- split-K over 64-row q-tiles (64 per batch), 64-key tiles, band 32 ----
// nch = qt/32 + 1 (1 or 2); NSLOT = 32 + 64 = 96/batch; grid 768 (= 3 blk/CU exactly).
// Balanced triples: {band0[a], band1[63-a]c0, band1[63-a]c1} = (a+1)+(64-a) = 65 steps.
static constexpr int NSLOT = 96;
static constexpr size_t WS_SPLITK =
    WS_NEED + (size_t)BATCH * NSLOT * (8192 + 64) * sizeof(float);   // ~42.1 MB

// 1/sqrt(128) * log2(e); folded into Q so the inner loop is bare exp2.
static constexpr float SCALE_LOG2E = 0.08838834764831845f * 1.4426950408889634f;

// S(qt) = slots before q-tile qt, band 32: g=qt>>5 (0|1) -> qt + (qt-32)*g
__device__ __forceinline__ int slot_base(int qt) {
  int g = qt >> 5;
  return qt + (qt - 32) * g;
}

// async global->LDS, 16B per lane; LDS dest = wave-uniform base + lane*16
__device__ __forceinline__ void gld16(bf16_t* l, const bf16_t* g) {
  __builtin_amdgcn_global_load_lds(
      (const __attribute__((address_space(1))) unsigned int*)g,
      (__attribute__((address_space(3))) unsigned int*)l, 16, 0, 0);
}

__device__ __forceinline__ bf16x8 ld8_f32s(const float* p, float s) {
  float4 a = *(const float4*)p;
  float4 b = *(const float4*)(p + 4);
  bf16x8 r = {(__bf16)(a.x * s), (__bf16)(a.y * s), (__bf16)(a.z * s), (__bf16)(a.w * s),
              (__bf16)(b.x * s), (__bf16)(b.y * s), (__bf16)(b.z * s), (__bf16)(b.w * s)};
  return r;
}

// ---------------- prep: K fp32->bf16 (16B stores), V fp32 -> Vt bf16 [B][dim][key] ----------------

__global__ __launch_bounds__(256)
void prep_kernel(const float* __restrict__ K, const float* __restrict__ V,
                 bf16_t* __restrict__ Kb, bf16_t* __restrict__ Vt) {
  __shared__ bf16_t ldsT[128 * 66];       // [dim][key], stride 66 to spread banks
  const int bid = blockIdx.x;
  if (bid < 1536) {                       // K convert, grid-stride, 16B stores
    const size_t n8 = NELEM / 8;
    for (size_t i = (size_t)bid * 256 + threadIdx.x; i < n8; i += (size_t)1536 * 256) {
      float4 a = ((const float4*)K)[2 * i];
      float4 c = ((const float4*)K)[2 * i + 1];
      bf16x8 kv = {(__bf16)a.x, (__bf16)a.y, (__bf16)a.z, (__bf16)a.w,
                   (__bf16)c.x, (__bf16)c.y, (__bf16)c.z, (__bf16)c.w};
      ((bf16x8*)Kb)[i] = kv;
    }
  } else {                                // V transpose+convert, one 64-key tile/block
    const int id = bid - 1536;            // 0..511
    const int b  = id & 7;
    const int kt = id >> 3;               // 0..63
    const float* src = V + ((size_t)(b * NSEQ + kt * 64)) * DIM;
    #pragma unroll
    for (int it = 0; it < 8; ++it) {
      const int idx = it * 256 + (int)threadIdx.x;   // 0..2047 float4
      const int k = idx >> 5, c4 = idx & 31;
      float4 v = ((const float4*)src)[idx];
      ldsT[(c4 * 4 + 0) * 66 + k] = (__bf16)v.x;
      ldsT[(c4 * 4 + 1) * 66 + k] = (__bf16)v.y;
      ldsT[(c4 * 4 + 2) * 66 + k] = (__bf16)v.z;
      ldsT[(c4 * 4 + 3) * 66 + k] = (__bf16)v.w;
    }
    __syncthreads();
    #pragma unroll
    for (int it = 0; it < 4; ++it) {
      const int task = it * 256 + (int)threadIdx.x;  // 0..1023
      const int d = task >> 3, kg = task & 7;
      bf16x8 o;
      #pragma unroll
      for (int j = 0; j < 8; ++j) o[j] = ldsT[d * 66 + kg * 8 + j];
      *(bf16x8*)(Vt + ((size_t)b * DIM + d) * NSEQ + kt * 64 + kg * 8) = o;
    }
  }
}

// ---------------- per-tile compute: 16q x 64k per wave, swapped QK^T, in-reg P ----------------
// K staged with row permutation pi so each lane's QK^T outputs ARE its PV A-fragment
// (keys 32h+8quad+4cc+r, lane-local); lane's q-column is l16. Verbatim best (r8/r13).

template <bool MASK>
__device__ __forceinline__ void tile16(
    const bf16_t* __restrict__ kbuf, const bf16_t* __restrict__ vbuf,
    const bf16x8 (&qf)[4], int l16, int quad, int wq16,
    floatx4 (&acc)[8], float& lsum) {
  #pragma unroll
  for (int h = 0; h < 2; ++h) {           // key half: 32h .. 32h+31
    float pr[8];                          // lane-local P values, keys 32h+8quad+{0..7}
    #pragma unroll
    for (int cc = 0; cc < 2; ++cc) {
      const int c4 = 2 * h + cc;
      floatx4 sv = {0.f, 0.f, 0.f, 0.f};
      const bf16_t* krow = kbuf + (c4 * 16 + l16) * DIM;
      #pragma unroll
      for (int d = 0; d < 4; ++d) {
        bf16x8 kf = *(const bf16x8*)(krow + (((4 * d + quad) ^ l16) * 8));
        sv = __builtin_amdgcn_mfma_f32_16x16x32_bf16(kf, qf[d], sv, 0, 0, 0);
      }
      #pragma unroll
      for (int r = 0; r < 4; ++r) {
        float v = sv[r];
        if constexpr (MASK) {
          const int key = 32 * h + 8 * quad + 4 * cc + r;        // pi-mapped key
          v = (key <= wq16 + l16) ? v : -3.0e38f;                // exp2 -> 0
        }
        float p = __builtin_amdgcn_exp2f(v);
        lsum += p;
        pr[4 * cc + r] = p;
      }
    }
    bf16x8 pf;
    #pragma unroll
    for (int j = 0; j < 8; ++j) pf[j] = (__bf16)pr[j];
    // ---- O += P(:,32h..32h+31) * V(32h..32h+31,:) ----
    __builtin_amdgcn_s_setprio(1);
    #pragma unroll
    for (int c = 0; c < 8; ++c) {
      const bf16_t* vrow = vbuf + (c * 16 + l16) * 64;
      bf16x8 vf = *(const bf16x8*)(vrow + (((quad + 4 * h) ^ (l16 & 7)) * 8));
      acc[c] = __builtin_amdgcn_mfma_f32_16x16x32_bf16(pf, vf, acc[c], 0, 0, 0);
    }
    __builtin_amdgcn_s_setprio(0);
  }
}

// ---------------- split-K attention: K-dbuf LDS + V reg-staged (48 KB), 3 blk/CU ----------------
// Inner loop verbatim round-8/13/14. Balanced-triple dispatch: round g=blockIdx>>8,
// position p=blockIdx&255 -> g=0/1: band-1 qt=63-(p>>3) chunks 0/1; g=2: band-0
// qt=p>>3. Blocks p, p+256, p+512 co-reside on one CU (round-robin) = 65 steps each.

__global__ __launch_bounds__(256, 3)
void causal_attn_splitk(const float* __restrict__ Qf, const bf16_t* __restrict__ Kb,
                        const bf16_t* __restrict__ Vt, float* __restrict__ Out,
                        float* __restrict__ Pp, float* __restrict__ Ls) {
  __shared__ __align__(16) bf16_t Kds[2][64 * DIM];   // 2 x 16 KB
  __shared__ __align__(16) bf16_t Vds[DIM * 64];      // 16 KB -> 48 KB total

  const int g = (int)blockIdx.x >> 8;                 // round 0,1,2
  const int p = (int)blockIdx.x & 255;
  const int b = p & 7;                                // batch -> XCD (L2 affinity)
  const int a = p >> 3;                               // 0..31
  const int qt  = (g == 2) ? a : 63 - a;
  const int cch = (g == 1) ? 1 : 0;
  const int ntot = qt + 1;                            // 64-key tiles for this q-tile
  const int nch  = (qt >> 5) + 1;
  const int nt_c = (ntot - 1 - cch) / nch + 1;        // tiles in this (strided) chunk
  const int nmask = (cch + (nt_c - 1) * nch == qt) ? 1 : 0;
  const int nfull = nt_c - nmask;

  const int tid  = (int)threadIdx.x;
  const int wave = tid >> 6;
  const int lane = tid & 63;
  const int l16  = lane & 15;
  const int quad = lane >> 4;
  const int wq16 = wave * 16;                         // wave's 16 q-rows within tile

  // Q fragments (B-operand): lane(l16,quad) = Q[q=wq16+l16][dims 32d+8quad..+8]
  bf16x8 qf[4];
  {
    const float* qrow =
        Qf + ((size_t)b * NSEQ + qt * 64 + wq16 + l16) * DIM + quad * 8;
    #pragma unroll
    for (int d = 0; d < 4; ++d) qf[d] = ld8_f32s(qrow + 32 * d, SCALE_LOG2E);
  }

  // staging: K rows permuted by pi, dim chunks XOR'd on SOURCE (gld16, linear dest).
  // V: prologue via gld16 (source-XOR); steady-state via regs: LINEAR global source,
  // XOR applied on the ds_write DEST. Readers unchanged.
  const bf16_t* kg = Kb + (size_t)b * NSEQ * DIM;
  const bf16_t* vg = Vt + ((size_t)b * DIM + 32 * wave) * NSEQ;
  int koff[4], voff[4], vsrc[4], vdst[4];
  #pragma unroll
  for (int i = 0; i < 4; ++i) {
    const int pp   = 16 * wave + 4 * i + quad;
    const int srow = 32 * (wave >> 1) + 8 * i + 4 * (wave & 1) + quad;  // pi(pp)
    koff[i] = srow * DIM + ((l16 ^ (pp & 15)) * 8);
    const int vrow = 8 * i + (lane >> 3);              // 0..31
    voff[i] = vrow * NSEQ + (((lane & 7) ^ (vrow & 7)) * 8);            // gld16 source
    vsrc[i] = vrow * NSEQ + (lane & 7) * 8;                             // reg source
    vdst[i] = (32 * wave + vrow) * 64 + (((lane & 7) ^ (vrow & 7)) * 8);// ds_write dest
  }

  floatx4 acc[8];
  #pragma unroll
  for (int c = 0; c < 8; ++c) acc[c] = (floatx4){0.f, 0.f, 0.f, 0.f};
  float lsum = 0.f;

  // prologue: stage tile cch (K -> buf 0, V -> single buffer), both via gld16
  {
    const size_t kb0 = (size_t)cch * 64;
    bf16_t* kl = &Kds[0][wave * 2048];
    bf16_t* vl = &Vds[wave * 2048];
    #pragma unroll
    for (int i = 0; i < 4; ++i) {
      gld16(kl + i * 512, kg + kb0 * DIM + koff[i]);
      gld16(vl + i * 512, vg + kb0 + voff[i]);
    }
  }
  __syncthreads();                        // drains vmcnt -> tile 0 ready

  bf16x8 vreg[4];
  int t = cch;
  for (int it = 0; it < nt_c; ++it, t += nch) {
    const int cur = it & 1;
    const bool more = (it + 1 < nt_c);    // block-uniform
    const size_t kbn = (size_t)(t + nch) * 64;
    if (more) {                           // K prefetch (LDS-direct) + V load-to-reg,
      bf16_t* kl = &Kds[cur ^ 1][wave * 2048];       // both hidden under compute
      #pragma unroll
      for (int i = 0; i < 4; ++i) gld16(kl + i * 512, kg + kbn * DIM + koff[i]);
      #pragma unroll
      for (int i = 0; i < 4; ++i) vreg[i] = *(const bf16x8*)(vg + kbn + vsrc[i]);
    }
    __builtin_amdgcn_sched_barrier(0);    // loads issue before compute
    if (it < nfull)
      tile16<false>(Kds[cur], Vds, qf, l16, quad, wq16, acc, lsum);
    else
      tile16<true>(Kds[cur], Vds, qf, l16, quad, wq16, acc, lsum);
    __builtin_amdgcn_sched_barrier(0);
    __builtin_amdgcn_s_barrier();         // all waves done reading Vds / Kds[cur]
    if (more) {
      // ds_write forces vmcnt wait on V regs (youngest) -> older K gld16 also retired
      #pragma unroll
      for (int i = 0; i < 4; ++i) *(bf16x8*)(&Vds[vdst[i]]) = vreg[i];
      asm volatile("s_waitcnt lgkmcnt(0)" ::: "memory");  // writes visible pre-barrier
      __builtin_amdgcn_sched_barrier(0);
      __builtin_amdgcn_s_barrier();       // staged tile visible to all waves
    }
  }

  // ---- l-reduction across quads (q = l16 per wave) ----
  float lred = lsum;
  lred += __shfl_xor(lred, 16, 64);
  lred += __shfl_xor(lred, 32, 64);

  if (nch == 1) {                                     // single chunk: direct output
    float invl[4];
    #pragma unroll
    for (int r = 0; r < 4; ++r)
      invl[r] = 1.0f / __shfl(lred, quad * 4 + r, 64);
    float* orow =
        Out + ((size_t)b * NSEQ + qt * 64 + wq16 + quad * 4) * DIM + l16;
    #pragma unroll
    for (int c = 0; c < 8; ++c)
      #pragma unroll
      for (int r = 0; r < 4; ++r)
        orow[(size_t)r * DIM + c * 16] = acc[c][r] * invl[r];
  } else {                                            // unnormalized partials
    const int slot = b * NSLOT + slot_base(qt) + cch;
    float* pb = Pp + (size_t)slot * 8192 +
                ((size_t)(wq16 + quad * 4)) * 128 + l16;
    #pragma unroll
    for (int c = 0; c < 8; ++c)
      #pragma unroll
      for (int r = 0; r < 4; ++r)
        pb[(size_t)r * 128 + c * 16] = acc[c][r];
    if (quad == 0)
      Ls[(size_t)slot * 64 + wq16 + l16] = lred;
  }
}

// ---------------- combine: sum 2 chunk partials, normalize, store (qt >= 32) ----------------
// 4 blocks per (b,qt): 16 q-rows each (1024 blocks).

__global__ __launch_bounds__(256)
void combine_kernel(const float* __restrict__ Pp, const float* __restrict__ Ls,
                    float* __restrict__ Out) {
  const int e    = (int)blockIdx.x >> 2;  // 8 batches x 32 qtiles
  const int qsub = (int)blockIdx.x & 3;
  const int b    = e & 7;
  const int qt   = 32 + (e >> 3);
  const int s0   = b * NSLOT + slot_base(qt);
  const int nch  = (qt >> 5) + 1;         // == 2
  const int t = (int)threadIdx.x;
  #pragma unroll
  for (int j = 0; j < 2; ++j) {
    const int idx = j * 256 + t;          // 0..511 float4 (16q x 32)
    const int q   = qsub * 16 + (idx >> 5);
    const int d4  = idx & 31;
    float4 v = {0.f, 0.f, 0.f, 0.f};
    float  l = 0.f;
    for (int ch = 0; ch < nch; ++ch) {
      const float* pc = Pp + (size_t)(s0 + ch) * 8192 + (size_t)q * 128 + d4 * 4;
      float4 a = *(const float4*)pc;
      v.x += a.x; v.y += a.y; v.z += a.z; v.w += a.w;
      l += Ls[(size_t)(s0 + ch) * 64 + q];
    }
    const float inv = 1.0f / l;
    float4 r = {v.x * inv, v.y * inv, v.z * inv, v.w * inv};
    *(float4*)(Out + ((size_t)b * NSEQ + qt * 64 + q) * DIM + d4 * 4) = r;
  }
}

// ---------------- middle tier: round-1 64q-row kernel (16.8MB <= ws < 42MB) ----------------

template <bool MASK>
__device__ __forceinline__ void tile_compute(
    const bf16_t* __restrict__ kbuf, const bf16_t* __restrict__ vbuf,
    bf16_t* __restrict__ pl, const bf16x8 (&qf)[4],
    int l16, int quad, int wq, floatx4 (&acc)[8], float (&lsum)[4]) {
  floatx4 s[4];
  #pragma unroll
  for (int c4 = 0; c4 < 4; ++c4) s[c4] = (floatx4){0.f, 0.f, 0.f, 0.f};
  #pragma unroll
  for (int c4 = 0; c4 < 4; ++c4) {
    const bf16_t* krow = kbuf + (c4 * 16 + l16) * DIM;
    #pragma unroll
    for (int d = 0; d < 4; ++d) {
      bf16x8 kf = *(const bf16x8*)(krow + (((4 * d + quad) ^ l16) * 8));
      s[c4] = __builtin_amdgcn_mfma_f32_16x16x32_bf16(qf[d], kf, s[c4], 0, 0, 0);
    }
  }
  #pragma unroll
  for (int c4 = 0; c4 < 4; ++c4) {
    #pragma unroll
    for (int r = 0; r < 4; ++r) {
      float v = s[c4][r];
      if constexpr (MASK)
        v = (c4 * 16 + l16 <= wq + quad * 4 + r) ? v : -3.0e38f;
      float p = __builtin_amdgcn_exp2f(v);
      lsum[r] += p;
      pl[(quad * 4 + r) * 72 + c4 * 16 + l16] = (__bf16)p;
    }
  }
  asm volatile("s_waitcnt lgkmcnt(0)" ::: "memory");
  bf16x8 pfA = *(const bf16x8*)(pl + l16 * 72 + quad * 8);
  bf16x8 pfB = *(const bf16x8*)(pl + l16 * 72 + 32 + quad * 8);
  #pragma unroll
  for (int c = 0; c < 8; ++c) {
    const bf16_t* vrow = vbuf + (c * 16 + l16) * 64;
    bf16x8 vfA = *(const bf16x8*)(vrow + ((quad ^ (l16 & 7)) * 8));
    bf16x8 vfB = *(const bf16x8*)(vrow + (((quad + 4) ^ (l16 & 7)) * 8));
    acc[c] = __builtin_amdgcn_mfma_f32_16x16x32_bf16(pfA, vfA, acc[c], 0, 0, 0);
    acc[c] = __builtin_amdgcn_mfma_f32_16x16x32_bf16(pfB, vfB, acc[c], 0, 0, 0);
  }
}

__global__ __launch_bounds__(256)
void causal_attn_kernel(const float* __restrict__ Qf, const bf16_t* __restrict__ Kb,
                        const bf16_t* __restrict__ Vt, float* __restrict__ Out) {
  __shared__ __align__(16) bf16_t Kbuf[64 * DIM];
  __shared__ __align__(16) bf16_t Vbuf[DIM * 64];
  __shared__ __align__(16) bf16_t Pbuf[4][16 * 72];

  const int half = blockIdx.x >> 8;
  const int idx  = blockIdx.x & 255;
  const int b    = idx & 7;
  const int q32  = idx >> 3;
  const int qt64 = half ? q32 : 63 - q32;

  const int tid  = (int)threadIdx.x;
  const int wave = tid >> 6;
  const int lane = tid & 63;
  const int l16  = lane & 15;
  const int quad = lane >> 4;
  const int wq   = wave * 16;

  bf16x8 qf[4];
  {
    const float* qrow = Qf + ((size_t)b * NSEQ + qt64 * 64 + wq + l16) * DIM + quad * 8;
    #pragma unroll
    for (int d = 0; d < 4; ++d) qf[d] = ld8_f32s(qrow + 32 * d, SCALE_LOG2E);
  }

  const bf16_t* kg0 = Kb + ((size_t)b * NSEQ + 16 * wave) * DIM;
  const bf16_t* vg0 = Vt + ((size_t)b * DIM + 32 * wave) * NSEQ;
  int koff[4], voff[4];
  #pragma unroll
  for (int i = 0; i < 4; ++i) {
    const int krow = 4 * i + (lane >> 4);
    koff[i] = krow * DIM + (((lane & 15) ^ (krow & 15)) * 8);
    const int vrow = 8 * i + (lane >> 3);
    voff[i] = vrow * NSEQ + (((lane & 7) ^ ((lane >> 3) & 7)) * 8);
  }
  bf16_t* kl = Kbuf + 16 * wave * DIM;
  bf16_t* vl = Vbuf + 32 * wave * 64;
  bf16_t* pl = Pbuf[wave];

  floatx4 acc[8];
  #pragma unroll
  for (int c = 0; c < 8; ++c) acc[c] = (floatx4){0.f, 0.f, 0.f, 0.f};
  float lsum[4] = {0.f, 0.f, 0.f, 0.f};

  const int nk = qt64 + 1;
  for (int kt = 0; kt < nk - 1; ++kt) {
    const int kb = kt * 64;
    #pragma unroll
    for (int i = 0; i < 4; ++i) gld16(kl + i * 512, kg0 + (size_t)kb * DIM + koff[i]);
    #pragma unroll
    for (int i = 0; i < 4; ++i) gld16(vl + i * 512, vg0 + kb + voff[i]);
    __syncthreads();
    tile_compute<false>(Kbuf, Vbuf, pl, qf, l16, quad, wq, acc, lsum);
    __syncthreads();
  }
  {
    const int kb = (nk - 1) * 64;
    #pragma unroll
    for (int i = 0; i < 4; ++i) gld16(kl + i * 512, kg0 + (size_t)kb * DIM + koff[i]);
    #pragma unroll
    for (int i = 0; i < 4; ++i) gld16(vl + i * 512, vg0 + kb + voff[i]);
    __syncthreads();
    tile_compute<true>(Kbuf, Vbuf, pl, qf, l16, quad, wq, acc, lsum);
  }

  float inv_l[4];
  #pragma unroll
  for (int r = 0; r < 4; ++r) {
    float s = lsum[r];
    #pragma unroll
    for (int off = 1; off < 16; off <<= 1) s += __shfl_xor(s, off, 64);
    inv_l[r] = 1.0f / s;
  }
  float* orow = Out + ((size_t)b * NSEQ + qt64 * 64 + wq + quad * 4) * DIM + l16;
  #pragma unroll
  for (int c = 0; c < 8; ++c) {
    #pragma unroll
    for (int r = 0; r < 4; ++r)
      orow[(size_t)r * DIM + c * 16] = acc[c][r] * inv_l[r];
  }
}

// ---------------- fallback (no workspace): fp32 direct ----------------

__global__ __launch_bounds__(256)
void causal_attn_fb(const float* __restrict__ Qf, const float* __restrict__ Kf,
                    const float* __restrict__ Vf, float* __restrict__ Out) {
  __shared__ bf16_t p_lds[4][16 * 72];
  const int bid = blockIdx.x, t = bid >> 3, b = bid & 7;
  const int tid = (int)threadIdx.x, wave = tid >> 6, lane = tid & 63;
  const int l16 = lane & 15, quad = lane >> 4;
  const int qtile = (wave < 2) ? t : (127 - t);
  const int q_base = qtile * 32 + (wave & 1) * 16;

  bf16x8 qf[4];
  const float* qrow = Qf + ((size_t)b * NSEQ + q_base + l16) * DIM + quad * 8;
  #pragma unroll
  for (int d = 0; d < 4; ++d) qf[d] = ld8_f32s(qrow + 32 * d, SCALE_LOG2E);

  floatx4 acc[8];
  #pragma unroll
  for (int c = 0; c < 8; ++c) acc[c] = (floatx4){0.f, 0.f, 0.f, 0.f};
  float lsum[4] = {0.f, 0.f, 0.f, 0.f};
  bf16_t* pl = p_lds[wave];
  const int ntiles = (q_base + 16 + 63) >> 6;

  for (int kt = 0; kt < ntiles; ++kt) {
    const int kb = kt * 64;
    floatx4 s[4];
    #pragma unroll
    for (int c4 = 0; c4 < 4; ++c4) s[c4] = (floatx4){0.f, 0.f, 0.f, 0.f};
    const float* kbase = Kf + ((size_t)b * NSEQ + kb + l16) * DIM + quad * 8;
    #pragma unroll
    for (int c4 = 0; c4 < 4; ++c4) {
      #pragma unroll
      for (int d = 0; d < 4; ++d) {
        bf16x8 kf = ld8_f32s(kbase + (size_t)c4 * 16 * DIM + 32 * d, 1.0f);
        s[c4] = __builtin_amdgcn_mfma_f32_16x16x32_bf16(qf[d], kf, s[c4], 0, 0, 0);
      }
    }
    #pragma unroll
    for (int c4 = 0; c4 < 4; ++c4) {
      #pragma unroll
      for (int r = 0; r < 4; ++r) {
        float v = s[c4][r];
        const int qi = q_base + quad * 4 + r;
        v = (kb + c4 * 16 + l16 <= qi) ? v : -3.0e38f;
        float p = __builtin_amdgcn_exp2f(v);
        lsum[r] += p;
        pl[(quad * 4 + r) * 72 + c4 * 16 + l16] = (__bf16)p;
      }
    }
    asm volatile("s_waitcnt lgkmcnt(0)" ::: "memory");
    bf16x8 pfA = *(const bf16x8*)(pl + l16 * 72 + quad * 8);
    bf16x8 pfB = *(const bf16x8*)(pl + l16 * 72 + 32 + quad * 8);
    const float* vb = Vf + ((size_t)b * NSEQ + kb) * DIM;
    #pragma unroll
    for (int c = 0; c < 8; ++c) {
      bf16x8 vfA, vfB;
      #pragma unroll
      for (int j = 0; j < 8; ++j) {
        vfA[j] = (__bf16)vb[(size_t)(quad * 8 + j) * DIM + c * 16 + l16];
        vfB[j] = (__bf16)vb[(size_t)(32 + quad * 8 + j) * DIM + c * 16 + l16];
      }
      acc[c] = __builtin_amdgcn_mfma_f32_16x16x32_bf16(pfA, vfA, acc[c], 0, 0, 0);
      acc[c] = __builtin_amdgcn_mfma_f32_16x16x32_bf16(pfB, vfB, acc[c], 0, 0, 0);
    }
  }
  float inv_l[4];
  #pragma unroll
  for (int r = 0; r < 4; ++r) {
    float s = lsum[r];
    #pragma unroll
    for (int off = 1; off < 16; off <<= 1) s += __shfl_xor(s, off, 64);
    inv_l[r] = 1.0f / s;
  }
  float* orow = Out + ((size_t)b * NSEQ + q_base + quad * 4) * DIM + l16;
  #pragma unroll
  for (int c = 0; c < 8; ++c) {
    #pragma unroll
    for (int r = 0; r < 4; ++r)
      orow[(size_t)r * DIM + c * 16] = acc[c][r] * inv_l[r];
  }
}

extern "C" void kernel_launch(void* const* d_in, const int* in_sizes, int n_in,
                              void* d_out, int out_size, void* d_ws, size_t ws_size,
                              hipStream_t stream) {
  const float* Q = (const float*)d_in[0];
  const float* K = (const float*)d_in[1];
  const float* V = (const float*)d_in[2];
  float* Out = (float*)d_out;
  (void)in_sizes; (void)n_in; (void)out_size;

  dim3 block(256);
  if (ws_size >= WS_SPLITK) {
    bf16_t* Kb = (bf16_t*)d_ws;
    bf16_t* Vt = Kb + NELEM;
    float*  Pp = (float*)((char*)d_ws + WS_NEED);
    float*  Ls = Pp + (size_t)BATCH * NSLOT * 8192;
    prep_kernel<<<dim3(2048), block, 0, stream>>>(K, V, Kb, Vt);
    causal_attn_splitk<<<dim3(BATCH * NSLOT), block, 0, stream>>>(Q, Kb, Vt, Out, Pp, Ls);
    combine_kernel<<<dim3(BATCH * 32 * 4), block, 0, stream>>>(Pp, Ls, Out);
  } else if (ws_size >= WS_NEED) {
    bf16_t* Kb = (bf16_t*)d_ws;
    bf16_t* Vt = Kb + NELEM;
    prep_kernel<<<dim3(2048), block, 0, stream>>>(K, V, Kb, Vt);
    causal_attn_kernel<<<dim3(512), block, 0, stream>>>(Q, Kb, Vt, Out);
  } else {
    causal_attn_fb<<<dim3(512), block, 0, stream>>>(Q, K, V, Out);
  }
}